// Round 1
// baseline (16566.275 us; speedup 1.0000x reference)
//
#include <hip/hip_runtime.h>

#define N_NODES 100000
#define N_EDGES 1600000

// ---- workspace layout (bytes) ----
#define OFF_OF    0UL            // o-chain f      [N,32]  f32  12.8e6
#define OFF_OAGG  12800000UL     // o-chain agg    [N,32]  f32  12.8e6
#define OFF_OHS   25600000UL     // hs_o           [N,128] f32  51.2e6
#define OFF_PNF   76800000UL     // pn f           [N,64]  f32  25.6e6
#define OFF_PNAGG 102400000UL    // pn agg         [N,64]  f32  25.6e6
#define OFF_PNHS  128000000UL    // hs_pn          [N,128] f32  51.2e6
#define OFF_DO    179200000UL    // Dinv_o         [N] f32
#define OFF_DP    179600000UL    // Dinv_p         [N] f32
#define OFF_DN    180000000UL    // Dinv_n         [N] f32
#define OFF_DEG   180400000UL    // deg            [N] i32
#define OFF_POS   180800000UL    // pos_deg        [N] i32
#define OFF_MASK  181200000UL    // pos mask       [E] u8

__global__ __launch_bounds__(256) void k_mask_deg(
    const int* __restrict__ src, const int* __restrict__ dst,
    const int* __restrict__ labels, unsigned char* __restrict__ mask,
    int* __restrict__ deg, int* __restrict__ posdeg) {
    int e = blockIdx.x * 256 + threadIdx.x;
    int s = src[e], d = dst[e];
    int p = (labels[s] == labels[d]) ? 1 : 0;
    mask[e] = (unsigned char)p;
    atomicAdd(&deg[d], 1);
    if (p) atomicAdd(&posdeg[d], 1);
}

__global__ __launch_bounds__(256) void k_dinv(
    const int* __restrict__ deg, const int* __restrict__ posdeg,
    float* __restrict__ d_o, float* __restrict__ d_p, float* __restrict__ d_n) {
    int v = blockIdx.x * 256 + threadIdx.x;
    if (v >= N_NODES) return;
    int dg = deg[v], pg = posdeg[v], ng = dg - pg;
    d_o[v] = rsqrtf((float)(dg > 1 ? dg : 1));
    d_p[v] = rsqrtf((float)(pg > 1 ? pg : 1));
    d_n[v] = rsqrtf((float)(ng > 1 ? ng : 1));
}

// init f buffers and the first poly heads of each group
__global__ __launch_bounds__(256) void k_init(
    const float* __restrict__ feat, float* __restrict__ o_f,
    float* __restrict__ o_hs, float* __restrict__ pn_f,
    float* __restrict__ pn_hs) {
    int idx = blockIdx.x * 256 + threadIdx.x;   // over N*32
    int v = idx >> 5, c = idx & 31;
    float x = feat[idx];
    o_f[idx] = x;
    o_hs[v * 128 + c] = 0.5f * x;            // THETAS[0][0]
    pn_f[v * 64 + c] = x;                    // p half
    pn_f[v * 64 + 32 + c] = x;               // n half
    pn_hs[v * 128 + c] = 0.5f * x;           // p poly0 head THETAS[0][0]
    pn_hs[v * 128 + 64 + c] = 0.1f * x;      // n poly0 head THETAS[2][0]
}

// o-chain edge scatter: agg[dst] += f[src]*Dinv[src]; 4 threads per edge
__global__ __launch_bounds__(256) void k_edge_o(
    const int* __restrict__ src, const int* __restrict__ dst,
    const float* __restrict__ f, const float* __restrict__ dinv,
    float* __restrict__ agg) {
    int t = blockIdx.x * 256 + threadIdx.x;
    int e = t >> 2, q = t & 3;
    int s = src[e], d = dst[e];
    float ds = dinv[s];
    const float4* fp = reinterpret_cast<const float4*>(f + s * 32 + q * 8);
    float4 a = fp[0], b = fp[1];
    float* ap = agg + d * 32 + q * 8;
    unsafeAtomicAdd(ap + 0, a.x * ds); unsafeAtomicAdd(ap + 1, a.y * ds);
    unsafeAtomicAdd(ap + 2, a.z * ds); unsafeAtomicAdd(ap + 3, a.w * ds);
    unsafeAtomicAdd(ap + 4, b.x * ds); unsafeAtomicAdd(ap + 5, b.y * ds);
    unsafeAtomicAdd(ap + 6, b.z * ds); unsafeAtomicAdd(ap + 7, b.w * ds);
}

// pn fused edge scatter: pos edges touch cols 0..31, neg edges cols 32..63
__global__ __launch_bounds__(256) void k_edge_pn(
    const int* __restrict__ src, const int* __restrict__ dst,
    const unsigned char* __restrict__ mask,
    const float* __restrict__ f, const float* __restrict__ dinv_p,
    const float* __restrict__ dinv_n, float* __restrict__ agg) {
    int t = blockIdx.x * 256 + threadIdx.x;
    int e = t >> 2, q = t & 3;
    int s = src[e], d = dst[e];
    int p = mask[e];
    int off = p ? 0 : 32;
    float ds = p ? dinv_p[s] : dinv_n[s];
    const float4* fp = reinterpret_cast<const float4*>(f + s * 64 + off + q * 8);
    float4 a = fp[0], b = fp[1];
    float* ap = agg + d * 64 + off + q * 8;
    unsafeAtomicAdd(ap + 0, a.x * ds); unsafeAtomicAdd(ap + 1, a.y * ds);
    unsafeAtomicAdd(ap + 2, a.z * ds); unsafeAtomicAdd(ap + 3, a.w * ds);
    unsafeAtomicAdd(ap + 4, b.x * ds); unsafeAtomicAdd(ap + 5, b.y * ds);
    unsafeAtomicAdd(ap + 6, b.z * ds); unsafeAtomicAdd(ap + 7, b.w * ds);
}

// o-chain node update: f = f - agg*Dinv; hs[colA] += cA*f; optional new-poly head hs[colB] = cB*f
__global__ __launch_bounds__(256) void k_node_o(
    float* __restrict__ f, const float* __restrict__ agg,
    const float* __restrict__ dinv, float* __restrict__ hs,
    int colA, float cA, int colB, float cB) {
    int idx = blockIdx.x * 256 + threadIdx.x;   // over N*32
    int v = idx >> 5, c = idx & 31;
    float fn = f[idx] - agg[idx] * dinv[v];
    f[idx] = fn;
    hs[v * 128 + colA + c] += cA * fn;
    if (colB >= 0) hs[v * 128 + colB + c] = cB * fn;
}

// pn node update: width 64; cols 0..31 are p (Dinv_p), 32..63 are n (Dinv_n)
__global__ __launch_bounds__(256) void k_node_pn(
    float* __restrict__ f, const float* __restrict__ agg,
    const float* __restrict__ dinv_p, const float* __restrict__ dinv_n,
    float* __restrict__ hs,
    int colAp, float cAp, int colAn, float cAn,
    int colB, float cBp, float cBn) {
    int idx = blockIdx.x * 256 + threadIdx.x;   // over N*64
    int v = idx >> 6, c = idx & 63;
    bool isn = c >= 32;
    int cc = c & 31;
    float dv = isn ? dinv_n[v] : dinv_p[v];
    float fn = f[idx] - agg[idx] * dv;
    f[idx] = fn;
    int colA = isn ? colAn : colAp;
    float cA = isn ? cAn : cAp;
    hs[v * 128 + colA + cc] += cA * fn;
    if (colB >= 0) {
        int cb = isn ? (colB + 64) : colB;
        float cB = isn ? cBn : cBp;
        hs[v * 128 + cb + cc] = cB * fn;
    }
}

// out[N,64] = act(X[N,KDIM] @ W[KDIM,64] + b); 4 rows per block
template <int KDIM, bool RELU>
__global__ __launch_bounds__(256) void k_gemm(
    const float* __restrict__ X, const float* __restrict__ W,
    const float* __restrict__ bias, float* __restrict__ out) {
    __shared__ float sW[KDIM * 64];
    __shared__ float sX[4 * KDIM];
    int tid = threadIdx.x;
    for (int i = tid; i < KDIM * 64; i += 256) sW[i] = W[i];
    int base = blockIdx.x * 4 * KDIM;
    for (int i = tid; i < 4 * KDIM; i += 256) sX[i] = X[base + i];
    __syncthreads();
    int rl = tid >> 6, c = tid & 63;
    float acc = bias[c];
#pragma unroll
    for (int k = 0; k < KDIM; ++k)
        acc = fmaf(sX[rl * KDIM + k], sW[k * 64 + c], acc);
    if (RELU) acc = acc > 0.f ? acc : 0.01f * acc;
    int row = blockIdx.x * 4 + rl;
    out[row * 64 + c] = acc;
}

extern "C" void kernel_launch(void* const* d_in, const int* in_sizes, int n_in,
                              void* d_out, int out_size, void* d_ws, size_t ws_size,
                              hipStream_t stream) {
    const float* feat   = (const float*)d_in[0];
    const int*   esrc   = (const int*)d_in[1];
    const int*   edst   = (const int*)d_in[2];
    const int*   labels = (const int*)d_in[3];
    const float* W_lin  = (const float*)d_in[4];
    const float* b_lin  = (const float*)d_in[5];
    const float* W_lin1 = (const float*)d_in[6];
    const float* b_lin1 = (const float*)d_in[7];
    const float* W_th   = (const float*)d_in[8];
    const float* b_th   = (const float*)d_in[9];

    char* ws = (char*)d_ws;
    float* o_f    = (float*)(ws + OFF_OF);
    float* o_agg  = (float*)(ws + OFF_OAGG);
    float* o_hs   = (float*)(ws + OFF_OHS);
    float* pn_f   = (float*)(ws + OFF_PNF);
    float* pn_agg = (float*)(ws + OFF_PNAGG);
    float* pn_hs  = (float*)(ws + OFF_PNHS);
    float* d_o    = (float*)(ws + OFF_DO);
    float* d_p    = (float*)(ws + OFF_DP);
    float* d_n    = (float*)(ws + OFF_DN);
    int*   deg    = (int*)(ws + OFF_DEG);
    int*   posdeg = (int*)(ws + OFF_POS);
    unsigned char* mask = (unsigned char*)(ws + OFF_MASK);

    float* out0 = (float*)d_out;                  // leaky(hs_o @ W_lin + b)
    float* out1 = out0 + (size_t)N_NODES * 64;    // leaky(hs_pn @ W_lin1 + b1)
    float* out2 = out1 + (size_t)N_NODES * 64;    // transh

    const float TH[4][3] = {{0.5f, -0.4f, 0.1f},
                            {0.25f, 0.5f, -0.25f},
                            {0.1f, 0.3f, 0.6f},
                            {0.05f, -0.2f, 0.8f}};

    // degrees + mask
    hipMemsetAsync(deg, 0, 2 * N_NODES * sizeof(int), stream);  // deg & posdeg contiguous
    k_mask_deg<<<N_EDGES / 256, 256, 0, stream>>>(esrc, edst, labels, mask, deg, posdeg);
    k_dinv<<<(N_NODES + 255) / 256, 256, 0, stream>>>(deg, posdeg, d_o, d_p, d_n);
    k_init<<<N_NODES * 32 / 256, 256, 0, stream>>>(feat, o_f, o_hs, pn_f, pn_hs);

    // o-chain: 8 hops over all edges
    for (int hop = 0; hop < 8; ++hop) {
        int poly = hop >> 1, k = (hop & 1) + 1;
        hipMemsetAsync(o_agg, 0, (size_t)N_NODES * 32 * sizeof(float), stream);
        k_edge_o<<<N_EDGES * 4 / 256, 256, 0, stream>>>(esrc, edst, o_f, d_o, o_agg);
        int colA = poly * 32;
        float cA = TH[poly][k];
        int colB = -1; float cB = 0.f;
        if (k == 2 && poly < 3) { colB = (poly + 1) * 32; cB = TH[poly + 1][0]; }
        k_node_o<<<N_NODES * 32 / 256, 256, 0, stream>>>(o_f, o_agg, d_o, o_hs, colA, cA, colB, cB);
    }

    // fused p+n chain: 4 hops, each edge contributes to exactly one half
    for (int hop = 0; hop < 4; ++hop) {
        int poly = hop >> 1, k = (hop & 1) + 1;
        hipMemsetAsync(pn_agg, 0, (size_t)N_NODES * 64 * sizeof(float), stream);
        k_edge_pn<<<N_EDGES * 4 / 256, 256, 0, stream>>>(esrc, edst, mask, pn_f, d_p, d_n, pn_agg);
        int colAp = poly * 32;           float cAp = TH[poly][k];
        int colAn = 64 + poly * 32;      float cAn = TH[poly + 2][k];
        int colB = -1; float cBp = 0.f, cBn = 0.f;
        if (k == 2 && poly == 0) { colB = 32; cBp = TH[1][0]; cBn = TH[3][0]; }
        k_node_pn<<<N_NODES * 64 / 256, 256, 0, stream>>>(pn_f, pn_agg, d_p, d_n, pn_hs,
                                                          colAp, cAp, colAn, cAn, colB, cBp, cBn);
    }

    // epilogues
    k_gemm<128, true><<<N_NODES / 4, 256, 0, stream>>>(o_hs, W_lin, b_lin, out0);
    k_gemm<128, true><<<N_NODES / 4, 256, 0, stream>>>(pn_hs, W_lin1, b_lin1, out1);
    k_gemm<32, false><<<N_NODES / 4, 256, 0, stream>>>(feat, W_th, b_th, out2);
}

// Round 3
// 1278.196 us; speedup vs baseline: 12.9607x; 12.9607x over previous
//
#include <hip/hip_runtime.h>

#define N_NODES 100000
#define N_EDGES 1600000

// ---- workspace layout (bytes) ----
#define OFF_G0    0UL            // g ping  [N,64] f32 (o-phase uses [N,32])
#define OFF_G1    25600000UL     // g pong  [N,64] f32
#define OFF_HS    51200000UL     // hs      [N,128] f32 (shared o-phase then pn-phase)
#define OFF_CSRA  102400000UL    // CSR all  src[E]
#define OFF_CSRP  108800000UL    // CSR pos  src[<=E]
#define OFF_CSRN  115200000UL    // CSR neg  src[<=E]
#define OFF_RPA   121600000UL    // rowptr all [N+1] (+pad)
#define OFF_RPP   122100000UL
#define OFF_RPN   122600000UL
#define OFF_CURA  123100000UL    // cursors [N]
#define OFF_CURP  123500000UL
#define OFF_CURN  123900000UL
#define OFF_DEG   124300000UL    // int [N]  (deg,pos,neg contiguous for one memset)
#define OFF_POSD  124700000UL
#define OFF_NEGD  125100000UL
#define OFF_D2O   125500000UL    // 1/clip(deg)     f32 [N]
#define OFF_D2P   125900000UL
#define OFF_D2N   126300000UL
#define OFF_RDO   126700000UL    // sqrt(clip(deg)) f32 [N]
#define OFF_RDP   127100000UL
#define OFF_RDN   127500000UL
#define OFF_DVO   127900000UL    // rsqrt(clip(deg)) f32 [N]
#define OFF_DVP   128300000UL
#define OFF_DVN   128700000UL
#define OFF_MASK  129100000UL    // u8 [E]
#define OFF_PART  130700000UL    // scan partials [392] int

__global__ __launch_bounds__(256) void k_mask_deg(
    const int* __restrict__ src, const int* __restrict__ dst,
    const int* __restrict__ labels, unsigned char* __restrict__ mask,
    int* __restrict__ deg, int* __restrict__ posdeg, int* __restrict__ negdeg) {
    int e = blockIdx.x * 256 + threadIdx.x;
    int s = src[e], d = dst[e];
    int p = (labels[s] == labels[d]) ? 1 : 0;
    mask[e] = (unsigned char)p;
    atomicAdd(&deg[d], 1);
    if (p) atomicAdd(&posdeg[d], 1);
    else   atomicAdd(&negdeg[d], 1);
}

__global__ __launch_bounds__(256) void k_dinv(
    const int* __restrict__ deg, const int* __restrict__ posdeg, const int* __restrict__ negdeg,
    float* __restrict__ d2o, float* __restrict__ d2p, float* __restrict__ d2n,
    float* __restrict__ rdo, float* __restrict__ rdp, float* __restrict__ rdn,
    float* __restrict__ dvo, float* __restrict__ dvp, float* __restrict__ dvn) {
    int v = blockIdx.x * 256 + threadIdx.x;
    if (v >= N_NODES) return;
    float co = (float)max(deg[v], 1);
    float cp = (float)max(posdeg[v], 1);
    float cn = (float)max(negdeg[v], 1);
    d2o[v] = 1.f / co; rdo[v] = sqrtf(co); dvo[v] = rsqrtf(co);
    d2p[v] = 1.f / cp; rdp[v] = sqrtf(cp); dvp[v] = rsqrtf(cp);
    d2n[v] = 1.f / cn; rdn[v] = sqrtf(cn); dvn[v] = rsqrtf(cn);
}

// ---- prefix scan (exclusive) over deg arrays, length N+1 outputs ----
__global__ __launch_bounds__(256) void k_scan_a(
    const int* __restrict__ in, int n, int* __restrict__ out, int* __restrict__ partial) {
    __shared__ int tmp[256];
    int g = blockIdx.x * 256 + threadIdx.x;
    int v = (g < n) ? in[g] : 0;
    tmp[threadIdx.x] = v;
    __syncthreads();
    for (int off = 1; off < 256; off <<= 1) {
        int t = (threadIdx.x >= off) ? tmp[threadIdx.x - off] : 0;
        __syncthreads();
        tmp[threadIdx.x] += t;
        __syncthreads();
    }
    out[g] = tmp[threadIdx.x] - v;   // exclusive (padding writes land in gap)
    if (threadIdx.x == 255) partial[blockIdx.x] = tmp[255];
}

__global__ __launch_bounds__(512) void k_scan_b(int* __restrict__ partial, int nb) {
    __shared__ int tmp[512];
    int v = (threadIdx.x < nb) ? partial[threadIdx.x] : 0;
    tmp[threadIdx.x] = v;
    __syncthreads();
    for (int off = 1; off < 512; off <<= 1) {
        int t = (threadIdx.x >= off) ? tmp[threadIdx.x - off] : 0;
        __syncthreads();
        tmp[threadIdx.x] += t;
        __syncthreads();
    }
    if (threadIdx.x < nb) partial[threadIdx.x] = tmp[threadIdx.x] - v;
}

__global__ __launch_bounds__(256) void k_scan_c(
    int* __restrict__ out, const int* __restrict__ partial, int n) {
    int g = blockIdx.x * 256 + threadIdx.x;
    if (g < n) out[g] += partial[blockIdx.x];
}

__global__ __launch_bounds__(256) void k_cur(
    const int* __restrict__ ra, const int* __restrict__ rp, const int* __restrict__ rn,
    int* __restrict__ ca, int* __restrict__ cp, int* __restrict__ cn) {
    int g = blockIdx.x * 256 + threadIdx.x;
    if (g < N_NODES) { ca[g] = ra[g]; cp[g] = rp[g]; cn[g] = rn[g]; }
}

__global__ __launch_bounds__(256) void k_fill(
    const int* __restrict__ src, const int* __restrict__ dst, const unsigned char* __restrict__ mask,
    int* __restrict__ cura, int* __restrict__ curp, int* __restrict__ curn,
    int* __restrict__ csra, int* __restrict__ csrp, int* __restrict__ csrn) {
    int e = blockIdx.x * 256 + threadIdx.x;
    int s = src[e], d = dst[e];
    csra[atomicAdd(&cura[d], 1)] = s;
    if (mask[e]) csrp[atomicAdd(&curp[d], 1)] = s;
    else         csrn[atomicAdd(&curn[d], 1)] = s;
}

// ---- phase inits: g = feat * dinv ----
__global__ __launch_bounds__(256) void k_init_o(
    const float* __restrict__ feat, const float* __restrict__ dvo,
    float* __restrict__ g0, float* __restrict__ hs) {
    int idx = blockIdx.x * 256 + threadIdx.x;   // over N*32
    int v = idx >> 5, c = idx & 31;
    float x = feat[idx];
    g0[idx] = x * dvo[v];
    hs[v * 128 + c] = 0.5f * x;                 // THETAS[0][0]
}

__global__ __launch_bounds__(256) void k_init_pn(
    const float* __restrict__ feat, const float* __restrict__ dvp, const float* __restrict__ dvn,
    float* __restrict__ g0, float* __restrict__ hs) {
    int idx = blockIdx.x * 256 + threadIdx.x;   // over N*32
    int v = idx >> 5, c = idx & 31;
    float x = feat[idx];
    g0[v * 64 + c]      = x * dvp[v];
    g0[v * 64 + 32 + c] = x * dvn[v];
    hs[v * 128 + c]      = 0.5f * x;            // THETAS[0][0] (p head)
    hs[v * 128 + 64 + c] = 0.1f * x;            // THETAS[2][0] (n head)
}

// ---- o-hop: one 32-lane group per node; g_new = g_old - (sum g_old[src]) * dinv2 ----
__global__ __launch_bounds__(256) void k_hop_o(
    const int* __restrict__ rowptr, const int* __restrict__ csr,
    const float* __restrict__ g_old, float* __restrict__ g_new,
    const float* __restrict__ d2, const float* __restrict__ rd,
    float* __restrict__ hs, int colA, float cA, int colB, float cB) {
    int t = blockIdx.x * 256 + threadIdx.x;
    int v = t >> 5, c = t & 31;
    int beg = rowptr[v], end = rowptr[v + 1];
    float acc = 0.f;
#pragma unroll 4
    for (int i = beg; i < end; ++i) {
        int s = csr[i];
        acc += g_old[s * 32 + c];
    }
    float gn = g_old[v * 32 + c] - acc * d2[v];
    g_new[v * 32 + c] = gn;
    float fn = gn * rd[v];
    hs[v * 128 + colA + c] += cA * fn;
    if (colB >= 0) hs[v * 128 + colB + c] = cB * fn;
}

// ---- pn-hop: 32-lane group per (node, half); half 0 = pos CSR, half 1 = neg CSR ----
__global__ __launch_bounds__(256) void k_hop_pn(
    const int* __restrict__ rp_p, const int* __restrict__ csr_p,
    const int* __restrict__ rp_n, const int* __restrict__ csr_n,
    const float* __restrict__ g_old, float* __restrict__ g_new,
    const float* __restrict__ d2p, const float* __restrict__ d2n,
    const float* __restrict__ rdp, const float* __restrict__ rdn,
    float* __restrict__ hs,
    int colAp, float cAp, int colAn, float cAn,
    int colB, float cBp, float cBn) {
    int t = blockIdx.x * 256 + threadIdx.x;
    int gid = t >> 5, c = t & 31;
    int v = gid >> 1, half = gid & 1;
    const int* rp  = half ? rp_n : rp_p;
    const int* cs  = half ? csr_n : csr_p;
    float d2 = half ? d2n[v] : d2p[v];
    float rd = half ? rdn[v] : rdp[v];
    int base = half * 32;
    int beg = rp[v], end = rp[v + 1];
    float acc = 0.f;
#pragma unroll 4
    for (int i = beg; i < end; ++i) {
        int s = cs[i];
        acc += g_old[s * 64 + base + c];
    }
    float gn = g_old[v * 64 + base + c] - acc * d2;
    g_new[v * 64 + base + c] = gn;
    float fn = gn * rd;
    int colA = half ? colAn : colAp;
    float cA = half ? cAn : cAp;
    hs[v * 128 + colA + c] += cA * fn;
    if (colB >= 0) {
        int cb = half ? (colB + 64) : colB;
        float cB = half ? cBn : cBp;
        hs[v * 128 + cb + c] = cB * fn;
    }
}

// out[N,64] = act(X[N,KDIM] @ W[KDIM,64] + b); 4 rows per block
template <int KDIM, bool RELU>
__global__ __launch_bounds__(256) void k_gemm(
    const float* __restrict__ X, const float* __restrict__ W,
    const float* __restrict__ bias, float* __restrict__ out) {
    __shared__ float sW[KDIM * 64];
    __shared__ float sX[4 * KDIM];
    int tid = threadIdx.x;
    for (int i = tid; i < KDIM * 64; i += 256) sW[i] = W[i];
    int base = blockIdx.x * 4 * KDIM;
    for (int i = tid; i < 4 * KDIM; i += 256) sX[i] = X[base + i];
    __syncthreads();
    int rl = tid >> 6, c = tid & 63;
    float acc = bias[c];
#pragma unroll
    for (int k = 0; k < KDIM; ++k)
        acc = fmaf(sX[rl * KDIM + k], sW[k * 64 + c], acc);
    if (RELU) acc = acc > 0.f ? acc : 0.01f * acc;
    int row = blockIdx.x * 4 + rl;
    out[row * 64 + c] = acc;
}

extern "C" void kernel_launch(void* const* d_in, const int* in_sizes, int n_in,
                              void* d_out, int out_size, void* d_ws, size_t ws_size,
                              hipStream_t stream) {
    const float* feat   = (const float*)d_in[0];
    const int*   esrc   = (const int*)d_in[1];
    const int*   edst   = (const int*)d_in[2];
    const int*   labels = (const int*)d_in[3];
    const float* W_lin  = (const float*)d_in[4];
    const float* b_lin  = (const float*)d_in[5];
    const float* W_lin1 = (const float*)d_in[6];
    const float* b_lin1 = (const float*)d_in[7];
    const float* W_th   = (const float*)d_in[8];
    const float* b_th   = (const float*)d_in[9];

    char* ws = (char*)d_ws;
    float* g0   = (float*)(ws + OFF_G0);
    float* g1   = (float*)(ws + OFF_G1);
    float* hs   = (float*)(ws + OFF_HS);
    int* csra   = (int*)(ws + OFF_CSRA);
    int* csrp   = (int*)(ws + OFF_CSRP);
    int* csrn   = (int*)(ws + OFF_CSRN);
    int* rpa    = (int*)(ws + OFF_RPA);
    int* rpp    = (int*)(ws + OFF_RPP);
    int* rpn    = (int*)(ws + OFF_RPN);
    int* cura   = (int*)(ws + OFF_CURA);
    int* curp   = (int*)(ws + OFF_CURP);
    int* curn   = (int*)(ws + OFF_CURN);
    int* deg    = (int*)(ws + OFF_DEG);
    int* posd   = (int*)(ws + OFF_POSD);
    int* negd   = (int*)(ws + OFF_NEGD);
    float* d2o  = (float*)(ws + OFF_D2O);
    float* d2p  = (float*)(ws + OFF_D2P);
    float* d2n  = (float*)(ws + OFF_D2N);
    float* rdo  = (float*)(ws + OFF_RDO);
    float* rdp  = (float*)(ws + OFF_RDP);
    float* rdn  = (float*)(ws + OFF_RDN);
    float* dvo  = (float*)(ws + OFF_DVO);
    float* dvp  = (float*)(ws + OFF_DVP);
    float* dvn  = (float*)(ws + OFF_DVN);
    unsigned char* mask = (unsigned char*)(ws + OFF_MASK);
    int* part   = (int*)(ws + OFF_PART);

    float* out0 = (float*)d_out;
    float* out1 = out0 + (size_t)N_NODES * 64;
    float* out2 = out1 + (size_t)N_NODES * 64;

    const float TH[4][3] = {{0.5f, -0.4f, 0.1f},
                            {0.25f, 0.5f, -0.25f},
                            {0.1f, 0.3f, 0.6f},
                            {0.05f, -0.2f, 0.8f}};

    const int EB = N_EDGES / 256;            // 6250
    const int NB = (N_NODES + 255) / 256;    // 391
    const int SB = (N_NODES + 256) / 256 + 1;// 392 blocks covers N+1 outputs

    // degrees + mask
    hipMemsetAsync(deg, 0, 3 * 400000, stream);   // deg,posd,negd contiguous
    k_mask_deg<<<EB, 256, 0, stream>>>(esrc, edst, labels, mask, deg, posd, negd);
    k_dinv<<<NB, 256, 0, stream>>>(deg, posd, negd, d2o, d2p, d2n, rdo, rdp, rdn, dvo, dvp, dvn);

    // CSR builds: exclusive scans -> rowptrs, then fill
    k_scan_a<<<SB, 256, 0, stream>>>(deg,  N_NODES, rpa, part);
    k_scan_b<<<1, 512, 0, stream>>>(part, SB);
    k_scan_c<<<SB, 256, 0, stream>>>(rpa, part, N_NODES + 1);
    k_scan_a<<<SB, 256, 0, stream>>>(posd, N_NODES, rpp, part);
    k_scan_b<<<1, 512, 0, stream>>>(part, SB);
    k_scan_c<<<SB, 256, 0, stream>>>(rpp, part, N_NODES + 1);
    k_scan_a<<<SB, 256, 0, stream>>>(negd, N_NODES, rpn, part);
    k_scan_b<<<1, 512, 0, stream>>>(part, SB);
    k_scan_c<<<SB, 256, 0, stream>>>(rpn, part, N_NODES + 1);
    k_cur<<<NB, 256, 0, stream>>>(rpa, rpp, rpn, cura, curp, curn);
    k_fill<<<EB, 256, 0, stream>>>(esrc, edst, mask, cura, curp, curn, csra, csrp, csrn);

    // ---- o-phase: 8 hops over all edges ----
    k_init_o<<<N_NODES * 32 / 256, 256, 0, stream>>>(feat, dvo, g0, hs);
    float* ga = g0; float* gb = g1;
    for (int hop = 0; hop < 8; ++hop) {
        int poly = hop >> 1, k = (hop & 1) + 1;
        int colA = poly * 32;
        float cA = TH[poly][k];
        int colB = -1; float cB = 0.f;
        if (k == 2 && poly < 3) { colB = (poly + 1) * 32; cB = TH[poly + 1][0]; }
        k_hop_o<<<N_NODES * 32 / 256, 256, 0, stream>>>(rpa, csra, ga, gb, d2o, rdo, hs, colA, cA, colB, cB);
        float* t = ga; ga = gb; gb = t;
    }
    k_gemm<128, true><<<N_NODES / 4, 256, 0, stream>>>(hs, W_lin, b_lin, out0);

    // ---- pn-phase: 4 fused hops ----
    k_init_pn<<<N_NODES * 32 / 256, 256, 0, stream>>>(feat, dvp, dvn, g0, hs);
    ga = g0; gb = g1;
    for (int hop = 0; hop < 4; ++hop) {
        int poly = hop >> 1, k = (hop & 1) + 1;
        int colAp = poly * 32;       float cAp = TH[poly][k];
        int colAn = 64 + poly * 32;  float cAn = TH[poly + 2][k];
        int colB = -1; float cBp = 0.f, cBn = 0.f;
        if (k == 2 && poly == 0) { colB = 32; cBp = TH[1][0]; cBn = TH[3][0]; }
        k_hop_pn<<<N_NODES * 64 / 256, 256, 0, stream>>>(rpp, csrp, rpn, csrn, ga, gb,
                                                         d2p, d2n, rdp, rdn, hs,
                                                         colAp, cAp, colAn, cAn, colB, cBp, cBn);
        float* t = ga; ga = gb; gb = t;
    }
    k_gemm<128, true><<<N_NODES / 4, 256, 0, stream>>>(hs, W_lin1, b_lin1, out1);

    // transh
    k_gemm<32, false><<<N_NODES / 4, 256, 0, stream>>>(feat, W_th, b_th, out2);
}

// Round 4
// 994.426 us; speedup vs baseline: 16.6591x; 1.2854x over previous
//
#include <hip/hip_runtime.h>

#define N_NODES 100000
#define N_EDGES 1600000

// ---- workspace layout (bytes) ----
#define OFF_G0    0UL            // g ping  [N,64] f32 (o-phase uses [N,32])
#define OFF_G1    25600000UL     // g pong  [N,64] f32
#define OFF_HS    51200000UL     // hs      [N,128] f32 (o-phase then pn-phase)
#define OFF_CSR   102400000UL    // tagged CSR: src | (neg<<31), [E] u32
#define OFF_RP    108800000UL    // rowptr [N+1] (+pad)
#define OFF_CUR   109300000UL    // cursors [N]
#define OFF_CNT   109700000UL    // packed deg<<16 | posdeg, [N] u32
#define OFF_D2O   110100000UL    // 1/clip(deg)     f32 [N]
#define OFF_D2P   110500000UL
#define OFF_D2N   110900000UL
#define OFF_RDO   111300000UL    // sqrt(clip(deg)) f32 [N]
#define OFF_RDP   111700000UL
#define OFF_RDN   112100000UL
#define OFF_DVO   112500000UL    // rsqrt(clip(deg)) f32 [N]
#define OFF_DVP   112900000UL
#define OFF_DVN   113300000UL
#define OFF_MASK  113700000UL    // u8 [E]
#define OFF_PART  115300000UL    // scan partials [392] int

__global__ __launch_bounds__(256) void k_mask_deg(
    const int* __restrict__ src, const int* __restrict__ dst,
    const int* __restrict__ labels, unsigned char* __restrict__ mask,
    unsigned int* __restrict__ cnt) {
    int e = blockIdx.x * 256 + threadIdx.x;
    int s = src[e], d = dst[e];
    int p = (labels[s] == labels[d]) ? 1 : 0;
    mask[e] = (unsigned char)p;
    atomicAdd(&cnt[d], 0x10000u + (unsigned)p);   // deg in hi16, posdeg in lo16
}

__global__ __launch_bounds__(256) void k_dinv(
    const unsigned int* __restrict__ cnt,
    float* __restrict__ d2o, float* __restrict__ d2p, float* __restrict__ d2n,
    float* __restrict__ rdo, float* __restrict__ rdp, float* __restrict__ rdn,
    float* __restrict__ dvo, float* __restrict__ dvp, float* __restrict__ dvn) {
    int v = blockIdx.x * 256 + threadIdx.x;
    if (v >= N_NODES) return;
    unsigned int c = cnt[v];
    int dg = (int)(c >> 16), pg = (int)(c & 0xFFFF), ng = dg - pg;
    float co = (float)max(dg, 1);
    float cp = (float)max(pg, 1);
    float cn = (float)max(ng, 1);
    d2o[v] = 1.f / co; rdo[v] = sqrtf(co); dvo[v] = rsqrtf(co);
    d2p[v] = 1.f / cp; rdp[v] = sqrtf(cp); dvp[v] = rsqrtf(cp);
    d2n[v] = 1.f / cn; rdn[v] = sqrtf(cn); dvn[v] = rsqrtf(cn);
}

// ---- exclusive prefix scan over deg (hi16 of cnt), N+1 outputs ----
__global__ __launch_bounds__(256) void k_scan_a(
    const unsigned int* __restrict__ cnt, int n, int* __restrict__ out,
    int* __restrict__ partial) {
    __shared__ int tmp[256];
    int g = blockIdx.x * 256 + threadIdx.x;
    int v = (g < n) ? (int)(cnt[g] >> 16) : 0;
    tmp[threadIdx.x] = v;
    __syncthreads();
    for (int off = 1; off < 256; off <<= 1) {
        int t = (threadIdx.x >= off) ? tmp[threadIdx.x - off] : 0;
        __syncthreads();
        tmp[threadIdx.x] += t;
        __syncthreads();
    }
    out[g] = tmp[threadIdx.x] - v;   // exclusive
    if (threadIdx.x == 255) partial[blockIdx.x] = tmp[255];
}

__global__ __launch_bounds__(512) void k_scan_b(int* __restrict__ partial, int nb) {
    __shared__ int tmp[512];
    int v = (threadIdx.x < nb) ? partial[threadIdx.x] : 0;
    tmp[threadIdx.x] = v;
    __syncthreads();
    for (int off = 1; off < 512; off <<= 1) {
        int t = (threadIdx.x >= off) ? tmp[threadIdx.x - off] : 0;
        __syncthreads();
        tmp[threadIdx.x] += t;
        __syncthreads();
    }
    if (threadIdx.x < nb) partial[threadIdx.x] = tmp[threadIdx.x] - v;
}

// add block offsets; also init cursor copy
__global__ __launch_bounds__(256) void k_scan_c(
    int* __restrict__ out, const int* __restrict__ partial, int n,
    int* __restrict__ cur) {
    int g = blockIdx.x * 256 + threadIdx.x;
    if (g < n) {
        int v = out[g] + partial[blockIdx.x];
        out[g] = v;
        if (g < N_NODES) cur[g] = v;
    }
}

__global__ __launch_bounds__(256) void k_fill(
    const int* __restrict__ src, const int* __restrict__ dst,
    const unsigned char* __restrict__ mask, int* __restrict__ cur,
    unsigned int* __restrict__ csr) {
    int e = blockIdx.x * 256 + threadIdx.x;
    int s = src[e], d = dst[e];
    unsigned int tag = mask[e] ? 0u : 0x80000000u;   // bit31 = neg edge
    csr[atomicAdd(&cur[d], 1)] = (unsigned int)s | tag;
}

// ---- phase inits: g = feat * dinv ----
__global__ __launch_bounds__(256) void k_init_o(
    const float* __restrict__ feat, const float* __restrict__ dvo,
    float* __restrict__ g0, float* __restrict__ hs) {
    int idx = blockIdx.x * 256 + threadIdx.x;   // over N*32
    int v = idx >> 5, c = idx & 31;
    float x = feat[idx];
    g0[idx] = x * dvo[v];
    hs[v * 128 + c] = 0.5f * x;                 // THETAS[0][0]
}

__global__ __launch_bounds__(256) void k_init_pn(
    const float* __restrict__ feat, const float* __restrict__ dvp, const float* __restrict__ dvn,
    float* __restrict__ g0, float* __restrict__ hs) {
    int idx = blockIdx.x * 256 + threadIdx.x;   // over N*32
    int v = idx >> 5, c = idx & 31;
    float x = feat[idx];
    g0[v * 64 + c]      = x * dvp[v];
    g0[v * 64 + 32 + c] = x * dvn[v];
    hs[v * 128 + c]      = 0.5f * x;            // THETAS[0][0] (p head)
    hs[v * 128 + 64 + c] = 0.1f * x;            // THETAS[2][0] (n head)
}

// ---- o-hop: one 32-lane group per node; g_new = g_old - (sum g_old[src]) * d2 ----
__global__ __launch_bounds__(256) void k_hop_o(
    const int* __restrict__ rowptr, const unsigned int* __restrict__ csr,
    const float* __restrict__ g_old, float* __restrict__ g_new,
    const float* __restrict__ d2, const float* __restrict__ rd,
    float* __restrict__ hs, int colA, float cA, int colB, float cB) {
    int t = blockIdx.x * 256 + threadIdx.x;
    int v = t >> 5, c = t & 31;
    int beg = rowptr[v], end = rowptr[v + 1];
    float acc = 0.f;
#pragma unroll 4
    for (int i = beg; i < end; ++i) {
        int s = (int)(csr[i] & 0x7FFFFFFFu);
        acc += g_old[s * 32 + c];
    }
    float gn = g_old[v * 32 + c] - acc * d2[v];
    g_new[v * 32 + c] = gn;
    float fn = gn * rd[v];
    hs[v * 128 + colA + c] += cA * fn;
    if (colB >= 0) hs[v * 128 + colB + c] = cB * fn;
}

// ---- pn-hop: 32-lane group per node processes BOTH halves via tagged CSR ----
__global__ __launch_bounds__(256) void k_hop_pn(
    const int* __restrict__ rowptr, const unsigned int* __restrict__ csr,
    const float* __restrict__ g_old, float* __restrict__ g_new,
    const float* __restrict__ d2p, const float* __restrict__ d2n,
    const float* __restrict__ rdp, const float* __restrict__ rdn,
    float* __restrict__ hs,
    int colAp, float cAp, int colAn, float cAn,
    int colB, float cBp, float cBn) {
    int t = blockIdx.x * 256 + threadIdx.x;
    int v = t >> 5, c = t & 31;
    int beg = rowptr[v], end = rowptr[v + 1];
    float accp = 0.f, accn = 0.f;
#pragma unroll 4
    for (int i = beg; i < end; ++i) {
        unsigned int e = csr[i];
        int s = (int)(e & 0x7FFFFFFFu);
        int neg = (int)(e >> 31);
        float val = g_old[s * 64 + (neg << 5) + c];
        accp += neg ? 0.f : val;
        accn += neg ? val : 0.f;
    }
    float gp = g_old[v * 64 + c]      - accp * d2p[v];
    float gn = g_old[v * 64 + 32 + c] - accn * d2n[v];
    g_new[v * 64 + c]      = gp;
    g_new[v * 64 + 32 + c] = gn;
    float fp = gp * rdp[v];
    float fn = gn * rdn[v];
    hs[v * 128 + colAp + c] += cAp * fp;
    hs[v * 128 + colAn + c] += cAn * fn;
    if (colB >= 0) {
        hs[v * 128 + colB + c]      = cBp * fp;
        hs[v * 128 + colB + 64 + c] = cBn * fn;
    }
}

// out[N,64] = act(X[N,KDIM] @ W[KDIM,64] + b); 4 rows per block
template <int KDIM, bool RELU>
__global__ __launch_bounds__(256) void k_gemm(
    const float* __restrict__ X, const float* __restrict__ W,
    const float* __restrict__ bias, float* __restrict__ out) {
    __shared__ float sW[KDIM * 64];
    __shared__ float sX[4 * KDIM];
    int tid = threadIdx.x;
    for (int i = tid; i < KDIM * 64; i += 256) sW[i] = W[i];
    int base = blockIdx.x * 4 * KDIM;
    for (int i = tid; i < 4 * KDIM; i += 256) sX[i] = X[base + i];
    __syncthreads();
    int rl = tid >> 6, c = tid & 63;
    float acc = bias[c];
#pragma unroll
    for (int k = 0; k < KDIM; ++k)
        acc = fmaf(sX[rl * KDIM + k], sW[k * 64 + c], acc);
    if (RELU) acc = acc > 0.f ? acc : 0.01f * acc;
    int row = blockIdx.x * 4 + rl;
    out[row * 64 + c] = acc;
}

extern "C" void kernel_launch(void* const* d_in, const int* in_sizes, int n_in,
                              void* d_out, int out_size, void* d_ws, size_t ws_size,
                              hipStream_t stream) {
    const float* feat   = (const float*)d_in[0];
    const int*   esrc   = (const int*)d_in[1];
    const int*   edst   = (const int*)d_in[2];
    const int*   labels = (const int*)d_in[3];
    const float* W_lin  = (const float*)d_in[4];
    const float* b_lin  = (const float*)d_in[5];
    const float* W_lin1 = (const float*)d_in[6];
    const float* b_lin1 = (const float*)d_in[7];
    const float* W_th   = (const float*)d_in[8];
    const float* b_th   = (const float*)d_in[9];

    char* ws = (char*)d_ws;
    float* g0   = (float*)(ws + OFF_G0);
    float* g1   = (float*)(ws + OFF_G1);
    float* hs   = (float*)(ws + OFF_HS);
    unsigned int* csr = (unsigned int*)(ws + OFF_CSR);
    int* rp     = (int*)(ws + OFF_RP);
    int* cur    = (int*)(ws + OFF_CUR);
    unsigned int* cnt = (unsigned int*)(ws + OFF_CNT);
    float* d2o  = (float*)(ws + OFF_D2O);
    float* d2p  = (float*)(ws + OFF_D2P);
    float* d2n  = (float*)(ws + OFF_D2N);
    float* rdo  = (float*)(ws + OFF_RDO);
    float* rdp  = (float*)(ws + OFF_RDP);
    float* rdn  = (float*)(ws + OFF_RDN);
    float* dvo  = (float*)(ws + OFF_DVO);
    float* dvp  = (float*)(ws + OFF_DVP);
    float* dvn  = (float*)(ws + OFF_DVN);
    unsigned char* mask = (unsigned char*)(ws + OFF_MASK);
    int* part   = (int*)(ws + OFF_PART);

    float* out0 = (float*)d_out;
    float* out1 = out0 + (size_t)N_NODES * 64;
    float* out2 = out1 + (size_t)N_NODES * 64;

    const float TH[4][3] = {{0.5f, -0.4f, 0.1f},
                            {0.25f, 0.5f, -0.25f},
                            {0.1f, 0.3f, 0.6f},
                            {0.05f, -0.2f, 0.8f}};

    const int EB = N_EDGES / 256;             // 6250
    const int NB = (N_NODES + 255) / 256;     // 391
    const int SB = (N_NODES + 256) / 256 + 1; // 392 blocks covers N+1 outputs

    // packed degree counters + mask
    hipMemsetAsync(cnt, 0, N_NODES * sizeof(int), stream);
    k_mask_deg<<<EB, 256, 0, stream>>>(esrc, edst, labels, mask, cnt);
    k_dinv<<<NB, 256, 0, stream>>>(cnt, d2o, d2p, d2n, rdo, rdp, rdn, dvo, dvp, dvn);

    // single CSR build: scan -> rowptr (+cursors), then tagged fill
    k_scan_a<<<SB, 256, 0, stream>>>(cnt, N_NODES, rp, part);
    k_scan_b<<<1, 512, 0, stream>>>(part, SB);
    k_scan_c<<<SB, 256, 0, stream>>>(rp, part, N_NODES + 1, cur);
    k_fill<<<EB, 256, 0, stream>>>(esrc, edst, mask, cur, csr);

    // ---- o-phase: 8 hops over all edges ----
    k_init_o<<<N_NODES * 32 / 256, 256, 0, stream>>>(feat, dvo, g0, hs);
    float* ga = g0; float* gb = g1;
    for (int hop = 0; hop < 8; ++hop) {
        int poly = hop >> 1, k = (hop & 1) + 1;
        int colA = poly * 32;
        float cA = TH[poly][k];
        int colB = -1; float cB = 0.f;
        if (k == 2 && poly < 3) { colB = (poly + 1) * 32; cB = TH[poly + 1][0]; }
        k_hop_o<<<N_NODES * 32 / 256, 256, 0, stream>>>(rp, csr, ga, gb, d2o, rdo, hs, colA, cA, colB, cB);
        float* t = ga; ga = gb; gb = t;
    }
    k_gemm<128, true><<<N_NODES / 4, 256, 0, stream>>>(hs, W_lin, b_lin, out0);

    // ---- pn-phase: 4 fused hops over tagged CSR ----
    k_init_pn<<<N_NODES * 32 / 256, 256, 0, stream>>>(feat, dvp, dvn, g0, hs);
    ga = g0; gb = g1;
    for (int hop = 0; hop < 4; ++hop) {
        int poly = hop >> 1, k = (hop & 1) + 1;
        int colAp = poly * 32;       float cAp = TH[poly][k];
        int colAn = 64 + poly * 32;  float cAn = TH[poly + 2][k];
        int colB = -1; float cBp = 0.f, cBn = 0.f;
        if (k == 2 && poly == 0) { colB = 32; cBp = TH[1][0]; cBn = TH[3][0]; }
        k_hop_pn<<<N_NODES * 32 / 256, 256, 0, stream>>>(rp, csr, ga, gb,
                                                         d2p, d2n, rdp, rdn, hs,
                                                         colAp, cAp, colAn, cAn, colB, cBp, cBn);
        float* t = ga; ga = gb; gb = t;
    }
    k_gemm<128, true><<<N_NODES / 4, 256, 0, stream>>>(hs, W_lin1, b_lin1, out1);

    // transh
    k_gemm<32, false><<<N_NODES / 4, 256, 0, stream>>>(feat, W_th, b_th, out2);
}

// Round 5
// 964.843 us; speedup vs baseline: 17.1699x; 1.0307x over previous
//
#include <hip/hip_runtime.h>

#define N_NODES 100000
#define N_EDGES 1600000

// ---- workspace layout (bytes) ----
#define OFF_G0    0UL            // g ping  [N,64] f32 (o-phase uses [N,32])
#define OFF_G1    25600000UL     // g pong  [N,64] f32
#define OFF_HS    51200000UL     // hs      [N,128] f32 (o-phase then pn-phase)
#define OFF_CSR   102400000UL    // tagged CSR: src | (neg<<31), [E] u32
#define OFF_RP    108800000UL    // rowptr/cursor [N] (+scan pad)
#define OFF_CNT   109300000UL    // packed deg<<16 | posdeg, [N] u32
#define OFF_D2O   110100000UL    // 1/clip(deg)     f32 [N]
#define OFF_D2P   110500000UL
#define OFF_D2N   110900000UL
#define OFF_RDO   111300000UL    // sqrt(clip(deg)) f32 [N]
#define OFF_RDP   111700000UL
#define OFF_RDN   112100000UL
#define OFF_DVO   112500000UL    // rsqrt(clip(deg)) f32 [N]
#define OFF_DVP   112900000UL
#define OFF_DVN   113300000UL
#define OFF_PART  113700000UL    // scan partials [392] int

__global__ __launch_bounds__(256) void k_mask_deg(
    const int* __restrict__ src, const int* __restrict__ dst,
    const int* __restrict__ labels, unsigned int* __restrict__ cnt) {
    int e = blockIdx.x * 256 + threadIdx.x;
    int s = src[e], d = dst[e];
    unsigned int p = (labels[s] == labels[d]) ? 1u : 0u;
    atomicAdd(&cnt[d], 0x10000u + p);   // deg in hi16, posdeg in lo16
}

__global__ __launch_bounds__(256) void k_dinv(
    const unsigned int* __restrict__ cnt,
    float* __restrict__ d2o, float* __restrict__ d2p, float* __restrict__ d2n,
    float* __restrict__ rdo, float* __restrict__ rdp, float* __restrict__ rdn,
    float* __restrict__ dvo, float* __restrict__ dvp, float* __restrict__ dvn) {
    int v = blockIdx.x * 256 + threadIdx.x;
    if (v >= N_NODES) return;
    unsigned int c = cnt[v];
    int dg = (int)(c >> 16), pg = (int)(c & 0xFFFF), ng = dg - pg;
    float co = (float)max(dg, 1);
    float cp = (float)max(pg, 1);
    float cn = (float)max(ng, 1);
    d2o[v] = 1.f / co; rdo[v] = sqrtf(co); dvo[v] = rsqrtf(co);
    d2p[v] = 1.f / cp; rdp[v] = sqrtf(cp); dvp[v] = rsqrtf(cp);
    d2n[v] = 1.f / cn; rdn[v] = sqrtf(cn); dvn[v] = rsqrtf(cn);
}

// ---- exclusive prefix scan over deg (hi16 of cnt) ----
__global__ __launch_bounds__(256) void k_scan_a(
    const unsigned int* __restrict__ cnt, int n, int* __restrict__ out,
    int* __restrict__ partial) {
    __shared__ int tmp[256];
    int g = blockIdx.x * 256 + threadIdx.x;
    int v = (g < n) ? (int)(cnt[g] >> 16) : 0;
    tmp[threadIdx.x] = v;
    __syncthreads();
    for (int off = 1; off < 256; off <<= 1) {
        int t = (threadIdx.x >= off) ? tmp[threadIdx.x - off] : 0;
        __syncthreads();
        tmp[threadIdx.x] += t;
        __syncthreads();
    }
    out[g] = tmp[threadIdx.x] - v;   // exclusive
    if (threadIdx.x == 255) partial[blockIdx.x] = tmp[255];
}

__global__ __launch_bounds__(512) void k_scan_b(int* __restrict__ partial, int nb) {
    __shared__ int tmp[512];
    int v = (threadIdx.x < nb) ? partial[threadIdx.x] : 0;
    tmp[threadIdx.x] = v;
    __syncthreads();
    for (int off = 1; off < 512; off <<= 1) {
        int t = (threadIdx.x >= off) ? tmp[threadIdx.x - off] : 0;
        __syncthreads();
        tmp[threadIdx.x] += t;
        __syncthreads();
    }
    if (threadIdx.x < nb) partial[threadIdx.x] = tmp[threadIdx.x] - v;
}

__global__ __launch_bounds__(256) void k_scan_c(
    int* __restrict__ out, const int* __restrict__ partial, int n) {
    int g = blockIdx.x * 256 + threadIdx.x;
    if (g < n) out[g] += partial[blockIdx.x];
}

// fill uses rp as cursors; after fill, rp[v] == end-of-row v (start of v+1)
__global__ __launch_bounds__(256) void k_fill(
    const int* __restrict__ src, const int* __restrict__ dst,
    const int* __restrict__ labels, int* __restrict__ rp,
    unsigned int* __restrict__ csr) {
    int e = blockIdx.x * 256 + threadIdx.x;
    int s = src[e], d = dst[e];
    unsigned int tag = (labels[s] == labels[d]) ? 0u : 0x80000000u;
    csr[atomicAdd(&rp[d], 1)] = (unsigned int)s | tag;
}

// ---- phase inits: g = feat * dinv ----
__global__ __launch_bounds__(256) void k_init_o(
    const float* __restrict__ feat, const float* __restrict__ dvo,
    float* __restrict__ g0, float* __restrict__ hs) {
    int idx = blockIdx.x * 256 + threadIdx.x;   // over N*32
    int v = idx >> 5, c = idx & 31;
    float x = feat[idx];
    g0[idx] = x * dvo[v];
    hs[v * 128 + c] = 0.5f * x;                 // THETAS[0][0]
}

__global__ __launch_bounds__(256) void k_init_pn(
    const float* __restrict__ feat, const float* __restrict__ dvp, const float* __restrict__ dvn,
    float* __restrict__ g0, float* __restrict__ hs) {
    int idx = blockIdx.x * 256 + threadIdx.x;   // over N*32
    int v = idx >> 5, c = idx & 31;
    float x = feat[idx];
    g0[v * 64 + c]      = x * dvp[v];
    g0[v * 64 + 32 + c] = x * dvn[v];
    hs[v * 128 + c]      = 0.5f * x;            // THETAS[0][0] (p head)
    hs[v * 128 + 64 + c] = 0.1f * x;            // THETAS[2][0] (n head)
}

// ---- o-hop: 1 node per wave64; 8 edge-slots x 8 lanes, float4 gathers ----
__global__ __launch_bounds__(256) void k_hop_o(
    const int* __restrict__ rowend, const unsigned int* __restrict__ csr,
    const float* __restrict__ g_old, float* __restrict__ g_new,
    const float* __restrict__ d2, const float* __restrict__ rd,
    float* __restrict__ hs, int colA, float cA, int colB, float cB) {
    int v = (blockIdx.x * 256 + threadIdx.x) >> 6;
    int lane = threadIdx.x & 63;
    int slot = lane >> 3, fl = lane & 7;
    int beg = v ? rowend[v - 1] : 0;
    int end = rowend[v];
    float4 acc = make_float4(0.f, 0.f, 0.f, 0.f);
    for (int i = beg + slot; i < end; i += 8) {
        int s = (int)(csr[i] & 0x7FFFFFFFu);
        float4 val = reinterpret_cast<const float4*>(g_old + s * 32)[fl];
        acc.x += val.x; acc.y += val.y; acc.z += val.z; acc.w += val.w;
    }
    for (int m = 8; m < 64; m <<= 1) {
        acc.x += __shfl_xor(acc.x, m);
        acc.y += __shfl_xor(acc.y, m);
        acc.z += __shfl_xor(acc.z, m);
        acc.w += __shfl_xor(acc.w, m);
    }
    if (slot == 0) {
        float dd = d2[v], rr = rd[v];
        float4 gv = reinterpret_cast<const float4*>(g_old + v * 32)[fl];
        float4 gn;
        gn.x = gv.x - acc.x * dd; gn.y = gv.y - acc.y * dd;
        gn.z = gv.z - acc.z * dd; gn.w = gv.w - acc.w * dd;
        reinterpret_cast<float4*>(g_new + v * 32)[fl] = gn;
        float4 fn;
        fn.x = gn.x * rr; fn.y = gn.y * rr; fn.z = gn.z * rr; fn.w = gn.w * rr;
        float4* hp = reinterpret_cast<float4*>(hs + v * 128 + colA) + fl;
        float4 h = *hp;
        h.x += cA * fn.x; h.y += cA * fn.y; h.z += cA * fn.z; h.w += cA * fn.w;
        *hp = h;
        if (colB >= 0) {
            float4 hb;
            hb.x = cB * fn.x; hb.y = cB * fn.y; hb.z = cB * fn.z; hb.w = cB * fn.w;
            reinterpret_cast<float4*>(hs + v * 128 + colB)[fl] = hb;
        }
    }
}

// ---- pn-hop: 1 node per wave64, tagged CSR, dual accumulators ----
__global__ __launch_bounds__(256) void k_hop_pn(
    const int* __restrict__ rowend, const unsigned int* __restrict__ csr,
    const float* __restrict__ g_old, float* __restrict__ g_new,
    const float* __restrict__ d2p, const float* __restrict__ d2n,
    const float* __restrict__ rdp, const float* __restrict__ rdn,
    float* __restrict__ hs,
    int colAp, float cAp, int colAn, float cAn,
    int colB, float cBp, float cBn) {
    int v = (blockIdx.x * 256 + threadIdx.x) >> 6;
    int lane = threadIdx.x & 63;
    int slot = lane >> 3, fl = lane & 7;
    int beg = v ? rowend[v - 1] : 0;
    int end = rowend[v];
    float4 ap = make_float4(0.f, 0.f, 0.f, 0.f);
    float4 an = make_float4(0.f, 0.f, 0.f, 0.f);
    for (int i = beg + slot; i < end; i += 8) {
        unsigned int e = csr[i];
        int s = (int)(e & 0x7FFFFFFFu);
        int neg = (int)(e >> 31);
        float4 val = reinterpret_cast<const float4*>(g_old + s * 64 + (neg << 5))[fl];
        float w = neg ? 0.f : 1.f;
        float u = 1.f - w;
        ap.x += w * val.x; ap.y += w * val.y; ap.z += w * val.z; ap.w += w * val.w;
        an.x += u * val.x; an.y += u * val.y; an.z += u * val.z; an.w += u * val.w;
    }
    for (int m = 8; m < 64; m <<= 1) {
        ap.x += __shfl_xor(ap.x, m); ap.y += __shfl_xor(ap.y, m);
        ap.z += __shfl_xor(ap.z, m); ap.w += __shfl_xor(ap.w, m);
        an.x += __shfl_xor(an.x, m); an.y += __shfl_xor(an.y, m);
        an.z += __shfl_xor(an.z, m); an.w += __shfl_xor(an.w, m);
    }
    if (slot == 0) {
        float dd = d2p[v], rr = rdp[v];
        float4 gv = reinterpret_cast<const float4*>(g_old + v * 64)[fl];
        float4 gn;
        gn.x = gv.x - ap.x * dd; gn.y = gv.y - ap.y * dd;
        gn.z = gv.z - ap.z * dd; gn.w = gv.w - ap.w * dd;
        reinterpret_cast<float4*>(g_new + v * 64)[fl] = gn;
        float4 fn;
        fn.x = gn.x * rr; fn.y = gn.y * rr; fn.z = gn.z * rr; fn.w = gn.w * rr;
        float4* hp = reinterpret_cast<float4*>(hs + v * 128 + colAp) + fl;
        float4 h = *hp;
        h.x += cAp * fn.x; h.y += cAp * fn.y; h.z += cAp * fn.z; h.w += cAp * fn.w;
        *hp = h;
        if (colB >= 0) {
            float4 hb;
            hb.x = cBp * fn.x; hb.y = cBp * fn.y; hb.z = cBp * fn.z; hb.w = cBp * fn.w;
            reinterpret_cast<float4*>(hs + v * 128 + colB)[fl] = hb;
        }
    } else if (slot == 1) {
        float dd = d2n[v], rr = rdn[v];
        float4 gv = reinterpret_cast<const float4*>(g_old + v * 64 + 32)[fl];
        float4 gn;
        gn.x = gv.x - an.x * dd; gn.y = gv.y - an.y * dd;
        gn.z = gv.z - an.z * dd; gn.w = gv.w - an.w * dd;
        reinterpret_cast<float4*>(g_new + v * 64 + 32)[fl] = gn;
        float4 fn;
        fn.x = gn.x * rr; fn.y = gn.y * rr; fn.z = gn.z * rr; fn.w = gn.w * rr;
        float4* hp = reinterpret_cast<float4*>(hs + v * 128 + colAn) + fl;
        float4 h = *hp;
        h.x += cAn * fn.x; h.y += cAn * fn.y; h.z += cAn * fn.z; h.w += cAn * fn.w;
        *hp = h;
        if (colB >= 0) {
            float4 hb;
            hb.x = cBn * fn.x; hb.y = cBn * fn.y; hb.z = cBn * fn.z; hb.w = cBn * fn.w;
            reinterpret_cast<float4*>(hs + v * 128 + colB + 64)[fl] = hb;
        }
    }
}

// out[N,64] = act(X[N,KDIM] @ W[KDIM,64] + b); 4 rows per block
template <int KDIM, bool RELU>
__global__ __launch_bounds__(256) void k_gemm(
    const float* __restrict__ X, const float* __restrict__ W,
    const float* __restrict__ bias, float* __restrict__ out) {
    __shared__ float sW[KDIM * 64];
    __shared__ float sX[4 * KDIM];
    int tid = threadIdx.x;
    for (int i = tid; i < KDIM * 64; i += 256) sW[i] = W[i];
    int base = blockIdx.x * 4 * KDIM;
    for (int i = tid; i < 4 * KDIM; i += 256) sX[i] = X[base + i];
    __syncthreads();
    int rl = tid >> 6, c = tid & 63;
    float acc = bias[c];
#pragma unroll
    for (int k = 0; k < KDIM; ++k)
        acc = fmaf(sX[rl * KDIM + k], sW[k * 64 + c], acc);
    if (RELU) acc = acc > 0.f ? acc : 0.01f * acc;
    int row = blockIdx.x * 4 + rl;
    out[row * 64 + c] = acc;
}

extern "C" void kernel_launch(void* const* d_in, const int* in_sizes, int n_in,
                              void* d_out, int out_size, void* d_ws, size_t ws_size,
                              hipStream_t stream) {
    const float* feat   = (const float*)d_in[0];
    const int*   esrc   = (const int*)d_in[1];
    const int*   edst   = (const int*)d_in[2];
    const int*   labels = (const int*)d_in[3];
    const float* W_lin  = (const float*)d_in[4];
    const float* b_lin  = (const float*)d_in[5];
    const float* W_lin1 = (const float*)d_in[6];
    const float* b_lin1 = (const float*)d_in[7];
    const float* W_th   = (const float*)d_in[8];
    const float* b_th   = (const float*)d_in[9];

    char* ws = (char*)d_ws;
    float* g0   = (float*)(ws + OFF_G0);
    float* g1   = (float*)(ws + OFF_G1);
    float* hs   = (float*)(ws + OFF_HS);
    unsigned int* csr = (unsigned int*)(ws + OFF_CSR);
    int* rp     = (int*)(ws + OFF_RP);
    unsigned int* cnt = (unsigned int*)(ws + OFF_CNT);
    float* d2o  = (float*)(ws + OFF_D2O);
    float* d2p  = (float*)(ws + OFF_D2P);
    float* d2n  = (float*)(ws + OFF_D2N);
    float* rdo  = (float*)(ws + OFF_RDO);
    float* rdp  = (float*)(ws + OFF_RDP);
    float* rdn  = (float*)(ws + OFF_RDN);
    float* dvo  = (float*)(ws + OFF_DVO);
    float* dvp  = (float*)(ws + OFF_DVP);
    float* dvn  = (float*)(ws + OFF_DVN);
    int* part   = (int*)(ws + OFF_PART);

    float* out0 = (float*)d_out;
    float* out1 = out0 + (size_t)N_NODES * 64;
    float* out2 = out1 + (size_t)N_NODES * 64;

    const float TH[4][3] = {{0.5f, -0.4f, 0.1f},
                            {0.25f, 0.5f, -0.25f},
                            {0.1f, 0.3f, 0.6f},
                            {0.05f, -0.2f, 0.8f}};

    const int EB = N_EDGES / 256;             // 6250
    const int NB = (N_NODES + 255) / 256;     // 391
    const int SB = (N_NODES + 255) / 256 + 1; // 392 (pad block for scan)
    const int HB = N_NODES / 4;               // 25000 blocks, 1 node/wave64

    // packed degree counters
    hipMemsetAsync(cnt, 0, N_NODES * sizeof(int), stream);
    k_mask_deg<<<EB, 256, 0, stream>>>(esrc, edst, labels, cnt);
    k_dinv<<<NB, 256, 0, stream>>>(cnt, d2o, d2p, d2n, rdo, rdp, rdn, dvo, dvp, dvn);

    // CSR build: exclusive scan -> rp (start ptrs), tagged fill mutates rp -> end ptrs
    k_scan_a<<<SB, 256, 0, stream>>>(cnt, N_NODES, rp, part);
    k_scan_b<<<1, 512, 0, stream>>>(part, SB);
    k_scan_c<<<SB, 256, 0, stream>>>(rp, part, N_NODES);
    k_fill<<<EB, 256, 0, stream>>>(esrc, edst, labels, rp, csr);

    // ---- o-phase: 8 hops over all edges ----
    k_init_o<<<N_NODES * 32 / 256, 256, 0, stream>>>(feat, dvo, g0, hs);
    float* ga = g0; float* gb = g1;
    for (int hop = 0; hop < 8; ++hop) {
        int poly = hop >> 1, k = (hop & 1) + 1;
        int colA = poly * 32;
        float cA = TH[poly][k];
        int colB = -1; float cB = 0.f;
        if (k == 2 && poly < 3) { colB = (poly + 1) * 32; cB = TH[poly + 1][0]; }
        k_hop_o<<<HB, 256, 0, stream>>>(rp, csr, ga, gb, d2o, rdo, hs, colA, cA, colB, cB);
        float* t = ga; ga = gb; gb = t;
    }
    k_gemm<128, true><<<N_NODES / 4, 256, 0, stream>>>(hs, W_lin, b_lin, out0);

    // ---- pn-phase: 4 fused hops over tagged CSR ----
    k_init_pn<<<N_NODES * 32 / 256, 256, 0, stream>>>(feat, dvp, dvn, g0, hs);
    ga = g0; gb = g1;
    for (int hop = 0; hop < 4; ++hop) {
        int poly = hop >> 1, k = (hop & 1) + 1;
        int colAp = poly * 32;       float cAp = TH[poly][k];
        int colAn = 64 + poly * 32;  float cAn = TH[poly + 2][k];
        int colB = -1; float cBp = 0.f, cBn = 0.f;
        if (k == 2 && poly == 0) { colB = 32; cBp = TH[1][0]; cBn = TH[3][0]; }
        k_hop_pn<<<HB, 256, 0, stream>>>(rp, csr, ga, gb,
                                         d2p, d2n, rdp, rdn, hs,
                                         colAp, cAp, colAn, cAn, colB, cBp, cBn);
        float* t = ga; ga = gb; gb = t;
    }
    k_gemm<128, true><<<N_NODES / 4, 256, 0, stream>>>(hs, W_lin1, b_lin1, out1);

    // transh
    k_gemm<32, false><<<N_NODES / 4, 256, 0, stream>>>(feat, W_th, b_th, out2);
}

// Round 6
// 838.275 us; speedup vs baseline: 19.7623x; 1.1510x over previous
//
#include <hip/hip_runtime.h>

#define N_NODES 100000
#define N_EDGES 1600000

// ---- workspace layout (bytes) ----
#define OFF_G0    0UL            // g ping  [N,64] f32 (o-phase uses [N,32])
#define OFF_G1    25600000UL     // g pong  [N,64] f32
#define OFF_HS    51200000UL     // hs      [N,128] f32 (o-phase then pn-phase)
#define OFF_CSR   102400000UL    // tagged CSR: src | (neg<<31), [E] u32
#define OFF_RP    108800000UL    // rowptr/cursor [N] (+scan pad)
#define OFF_CNT   109300000UL    // packed deg<<16 | posdeg, [N] u32
#define OFF_D2O   110100000UL    // 1/clip(deg)     f32 [N]
#define OFF_D2P   110500000UL
#define OFF_D2N   110900000UL
#define OFF_RDO   111300000UL    // sqrt(clip(deg)) f32 [N]
#define OFF_RDP   111700000UL
#define OFF_RDN   112100000UL
#define OFF_DVO   112500000UL    // rsqrt(clip(deg)) f32 [N]
#define OFF_DVP   112900000UL
#define OFF_DVN   113300000UL
#define OFF_PART  113700000UL    // scan partials [392] int

__global__ __launch_bounds__(256) void k_mask_deg(
    const int* __restrict__ src, const int* __restrict__ dst,
    const int* __restrict__ labels, unsigned int* __restrict__ cnt) {
    int e = blockIdx.x * 256 + threadIdx.x;
    int s = src[e], d = dst[e];
    unsigned int p = (labels[s] == labels[d]) ? 1u : 0u;
    atomicAdd(&cnt[d], 0x10000u + p);   // deg in hi16, posdeg in lo16
}

__global__ __launch_bounds__(256) void k_dinv(
    const unsigned int* __restrict__ cnt,
    float* __restrict__ d2o, float* __restrict__ d2p, float* __restrict__ d2n,
    float* __restrict__ rdo, float* __restrict__ rdp, float* __restrict__ rdn,
    float* __restrict__ dvo, float* __restrict__ dvp, float* __restrict__ dvn) {
    int v = blockIdx.x * 256 + threadIdx.x;
    if (v >= N_NODES) return;
    unsigned int c = cnt[v];
    int dg = (int)(c >> 16), pg = (int)(c & 0xFFFF), ng = dg - pg;
    float co = (float)max(dg, 1);
    float cp = (float)max(pg, 1);
    float cn = (float)max(ng, 1);
    d2o[v] = 1.f / co; rdo[v] = sqrtf(co); dvo[v] = rsqrtf(co);
    d2p[v] = 1.f / cp; rdp[v] = sqrtf(cp); dvp[v] = rsqrtf(cp);
    d2n[v] = 1.f / cn; rdn[v] = sqrtf(cn); dvn[v] = rsqrtf(cn);
}

// ---- exclusive prefix scan over deg (hi16 of cnt) ----
__global__ __launch_bounds__(256) void k_scan_a(
    const unsigned int* __restrict__ cnt, int n, int* __restrict__ out,
    int* __restrict__ partial) {
    __shared__ int tmp[256];
    int g = blockIdx.x * 256 + threadIdx.x;
    int v = (g < n) ? (int)(cnt[g] >> 16) : 0;
    tmp[threadIdx.x] = v;
    __syncthreads();
    for (int off = 1; off < 256; off <<= 1) {
        int t = (threadIdx.x >= off) ? tmp[threadIdx.x - off] : 0;
        __syncthreads();
        tmp[threadIdx.x] += t;
        __syncthreads();
    }
    out[g] = tmp[threadIdx.x] - v;   // exclusive
    if (threadIdx.x == 255) partial[blockIdx.x] = tmp[255];
}

__global__ __launch_bounds__(512) void k_scan_b(int* __restrict__ partial, int nb) {
    __shared__ int tmp[512];
    int v = (threadIdx.x < nb) ? partial[threadIdx.x] : 0;
    tmp[threadIdx.x] = v;
    __syncthreads();
    for (int off = 1; off < 512; off <<= 1) {
        int t = (threadIdx.x >= off) ? tmp[threadIdx.x - off] : 0;
        __syncthreads();
        tmp[threadIdx.x] += t;
        __syncthreads();
    }
    if (threadIdx.x < nb) partial[threadIdx.x] = tmp[threadIdx.x] - v;
}

__global__ __launch_bounds__(256) void k_scan_c(
    int* __restrict__ out, const int* __restrict__ partial, int n) {
    int g = blockIdx.x * 256 + threadIdx.x;
    if (g < n) out[g] += partial[blockIdx.x];
}

// fill uses rp as cursors; after fill, rp[v] == end-of-row v (start of v+1)
__global__ __launch_bounds__(256) void k_fill(
    const int* __restrict__ src, const int* __restrict__ dst,
    const int* __restrict__ labels, int* __restrict__ rp,
    unsigned int* __restrict__ csr) {
    int e = blockIdx.x * 256 + threadIdx.x;
    int s = src[e], d = dst[e];
    unsigned int tag = (labels[s] == labels[d]) ? 0u : 0x80000000u;
    csr[atomicAdd(&rp[d], 1)] = (unsigned int)s | tag;
}

// ---- phase inits: g = feat * dinv ----
__global__ __launch_bounds__(256) void k_init_o(
    const float* __restrict__ feat, const float* __restrict__ dvo,
    float* __restrict__ g0, float* __restrict__ hs) {
    int idx = blockIdx.x * 256 + threadIdx.x;   // over N*32
    int v = idx >> 5, c = idx & 31;
    float x = feat[idx];
    g0[idx] = x * dvo[v];
    hs[v * 128 + c] = 0.5f * x;                 // THETAS[0][0]
}

__global__ __launch_bounds__(256) void k_init_pn(
    const float* __restrict__ feat, const float* __restrict__ dvp, const float* __restrict__ dvn,
    float* __restrict__ g0, float* __restrict__ hs) {
    int idx = blockIdx.x * 256 + threadIdx.x;   // over N*32
    int v = idx >> 5, c = idx & 31;
    float x = feat[idx];
    g0[v * 64 + c]      = x * dvp[v];
    g0[v * 64 + 32 + c] = x * dvn[v];
    hs[v * 128 + c]      = 0.5f * x;            // THETAS[0][0] (p head)
    hs[v * 128 + 64 + c] = 0.1f * x;            // THETAS[2][0] (n head)
}

// ---- o-hop: 1 node per wave64; 8 edge-slots x 8 lanes, float4 gathers ----
__global__ __launch_bounds__(256) void k_hop_o(
    const int* __restrict__ rowend, const unsigned int* __restrict__ csr,
    const float* __restrict__ g_old, float* __restrict__ g_new,
    const float* __restrict__ d2, const float* __restrict__ rd,
    float* __restrict__ hs, int colA, float cA, int colB, float cB) {
    int v = (blockIdx.x * 256 + threadIdx.x) >> 6;
    int lane = threadIdx.x & 63;
    int slot = lane >> 3, fl = lane & 7;
    int beg = v ? rowend[v - 1] : 0;
    int end = rowend[v];
    float4 acc = make_float4(0.f, 0.f, 0.f, 0.f);
    for (int i = beg + slot; i < end; i += 8) {
        int s = (int)(csr[i] & 0x7FFFFFFFu);
        float4 val = reinterpret_cast<const float4*>(g_old + s * 32)[fl];
        acc.x += val.x; acc.y += val.y; acc.z += val.z; acc.w += val.w;
    }
    for (int m = 8; m < 64; m <<= 1) {
        acc.x += __shfl_xor(acc.x, m);
        acc.y += __shfl_xor(acc.y, m);
        acc.z += __shfl_xor(acc.z, m);
        acc.w += __shfl_xor(acc.w, m);
    }
    if (slot == 0) {
        float dd = d2[v], rr = rd[v];
        float4 gv = reinterpret_cast<const float4*>(g_old + v * 32)[fl];
        float4 gn;
        gn.x = gv.x - acc.x * dd; gn.y = gv.y - acc.y * dd;
        gn.z = gv.z - acc.z * dd; gn.w = gv.w - acc.w * dd;
        reinterpret_cast<float4*>(g_new + v * 32)[fl] = gn;
        float4 fn;
        fn.x = gn.x * rr; fn.y = gn.y * rr; fn.z = gn.z * rr; fn.w = gn.w * rr;
        float4* hp = reinterpret_cast<float4*>(hs + v * 128 + colA) + fl;
        float4 h = *hp;
        h.x += cA * fn.x; h.y += cA * fn.y; h.z += cA * fn.z; h.w += cA * fn.w;
        *hp = h;
        if (colB >= 0) {
            float4 hb;
            hb.x = cB * fn.x; hb.y = cB * fn.y; hb.z = cB * fn.z; hb.w = cB * fn.w;
            reinterpret_cast<float4*>(hs + v * 128 + colB)[fl] = hb;
        }
    }
}

// ---- pn-hop: 1 node per wave64, tagged CSR, dual accumulators ----
__global__ __launch_bounds__(256) void k_hop_pn(
    const int* __restrict__ rowend, const unsigned int* __restrict__ csr,
    const float* __restrict__ g_old, float* __restrict__ g_new,
    const float* __restrict__ d2p, const float* __restrict__ d2n,
    const float* __restrict__ rdp, const float* __restrict__ rdn,
    float* __restrict__ hs,
    int colAp, float cAp, int colAn, float cAn,
    int colB, float cBp, float cBn) {
    int v = (blockIdx.x * 256 + threadIdx.x) >> 6;
    int lane = threadIdx.x & 63;
    int slot = lane >> 3, fl = lane & 7;
    int beg = v ? rowend[v - 1] : 0;
    int end = rowend[v];
    float4 ap = make_float4(0.f, 0.f, 0.f, 0.f);
    float4 an = make_float4(0.f, 0.f, 0.f, 0.f);
    for (int i = beg + slot; i < end; i += 8) {
        unsigned int e = csr[i];
        int s = (int)(e & 0x7FFFFFFFu);
        int neg = (int)(e >> 31);
        float4 val = reinterpret_cast<const float4*>(g_old + s * 64 + (neg << 5))[fl];
        float w = neg ? 0.f : 1.f;
        float u = 1.f - w;
        ap.x += w * val.x; ap.y += w * val.y; ap.z += w * val.z; ap.w += w * val.w;
        an.x += u * val.x; an.y += u * val.y; an.z += u * val.z; an.w += u * val.w;
    }
    for (int m = 8; m < 64; m <<= 1) {
        ap.x += __shfl_xor(ap.x, m); ap.y += __shfl_xor(ap.y, m);
        ap.z += __shfl_xor(ap.z, m); ap.w += __shfl_xor(ap.w, m);
        an.x += __shfl_xor(an.x, m); an.y += __shfl_xor(an.y, m);
        an.z += __shfl_xor(an.z, m); an.w += __shfl_xor(an.w, m);
    }
    if (slot == 0) {
        float dd = d2p[v], rr = rdp[v];
        float4 gv = reinterpret_cast<const float4*>(g_old + v * 64)[fl];
        float4 gn;
        gn.x = gv.x - ap.x * dd; gn.y = gv.y - ap.y * dd;
        gn.z = gv.z - ap.z * dd; gn.w = gv.w - ap.w * dd;
        reinterpret_cast<float4*>(g_new + v * 64)[fl] = gn;
        float4 fn;
        fn.x = gn.x * rr; fn.y = gn.y * rr; fn.z = gn.z * rr; fn.w = gn.w * rr;
        float4* hp = reinterpret_cast<float4*>(hs + v * 128 + colAp) + fl;
        float4 h = *hp;
        h.x += cAp * fn.x; h.y += cAp * fn.y; h.z += cAp * fn.z; h.w += cAp * fn.w;
        *hp = h;
        if (colB >= 0) {
            float4 hb;
            hb.x = cBp * fn.x; hb.y = cBp * fn.y; hb.z = cBp * fn.z; hb.w = cBp * fn.w;
            reinterpret_cast<float4*>(hs + v * 128 + colB)[fl] = hb;
        }
    } else if (slot == 1) {
        float dd = d2n[v], rr = rdn[v];
        float4 gv = reinterpret_cast<const float4*>(g_old + v * 64 + 32)[fl];
        float4 gn;
        gn.x = gv.x - an.x * dd; gn.y = gv.y - an.y * dd;
        gn.z = gv.z - an.z * dd; gn.w = gv.w - an.w * dd;
        reinterpret_cast<float4*>(g_new + v * 64 + 32)[fl] = gn;
        float4 fn;
        fn.x = gn.x * rr; fn.y = gn.y * rr; fn.z = gn.z * rr; fn.w = gn.w * rr;
        float4* hp = reinterpret_cast<float4*>(hs + v * 128 + colAn) + fl;
        float4 h = *hp;
        h.x += cAn * fn.x; h.y += cAn * fn.y; h.z += cAn * fn.z; h.w += cAn * fn.w;
        *hp = h;
        if (colB >= 0) {
            float4 hb;
            hb.x = cBn * fn.x; hb.y = cBn * fn.y; hb.z = cBn * fn.z; hb.w = cBn * fn.w;
            reinterpret_cast<float4*>(hs + v * 128 + colB + 64)[fl] = hb;
        }
    }
}

// ---- GEMM: out[N,64] = act(X[N,KDIM] @ W[KDIM,64] + b) ----
// 64 rows/block, 256 threads, 4x4 register tile per thread.
// sX row-major padded (stride SXP) so the 4-row b128 reads are 2-way-bank (free).
template <int KDIM, bool RELU>
__global__ __launch_bounds__(256) void k_gemm(
    const float* __restrict__ X, const float* __restrict__ W,
    const float* __restrict__ bias, float* __restrict__ out, int nrows) {
    constexpr int SXP = KDIM + 4;                // 132 or 36 (16B-aligned, 2-way banks)
    __shared__ float sW[KDIM * 64];
    __shared__ float sX[64 * SXP];
    int tid = threadIdx.x;
    int rowbase = blockIdx.x * 64;

    // stage W (row-major, float4, coalesced)
    for (int i = tid; i < KDIM * 16; i += 256)
        reinterpret_cast<float4*>(sW)[i] = reinterpret_cast<const float4*>(W)[i];

    // stage X rows (float4, coalesced; zero-pad rows >= nrows)
    constexpr int QF4 = KDIM / 4;                // float4 per row: 32 or 8
    constexpr int RPP = 256 / QF4;               // rows per pass: 8 or 32
    int q = tid & (QF4 - 1);
    int rloc = tid / QF4;
#pragma unroll
    for (int pass = 0; pass < 64 / RPP; ++pass) {
        int r = rloc + pass * RPP;
        int rg = rowbase + r;
        float4 v = make_float4(0.f, 0.f, 0.f, 0.f);
        if (rg < nrows) v = reinterpret_cast<const float4*>(X + (size_t)rg * KDIM)[q];
        float* dst = sX + r * SXP + q * 4;
        dst[0] = v.x; dst[1] = v.y; dst[2] = v.z; dst[3] = v.w;
    }
    __syncthreads();

    int c0 = (tid & 15) * 4;       // 4 contiguous cols
    int r0 = (tid >> 4) * 4;       // 4 contiguous rows
    float4 bv = reinterpret_cast<const float4*>(bias)[tid & 15];
    float4 acc0 = bv, acc1 = bv, acc2 = bv, acc3 = bv;

#pragma unroll 4
    for (int k4 = 0; k4 < KDIM / 4; ++k4) {
        int k = k4 * 4;
        float4 x0 = *reinterpret_cast<const float4*>(sX + (r0 + 0) * SXP + k);
        float4 x1 = *reinterpret_cast<const float4*>(sX + (r0 + 1) * SXP + k);
        float4 x2 = *reinterpret_cast<const float4*>(sX + (r0 + 2) * SXP + k);
        float4 x3 = *reinterpret_cast<const float4*>(sX + (r0 + 3) * SXP + k);
        float4 w0 = *reinterpret_cast<const float4*>(sW + (k + 0) * 64 + c0);
        float4 w1 = *reinterpret_cast<const float4*>(sW + (k + 1) * 64 + c0);
        float4 w2 = *reinterpret_cast<const float4*>(sW + (k + 2) * 64 + c0);
        float4 w3 = *reinterpret_cast<const float4*>(sW + (k + 3) * 64 + c0);
#define FMA4(A, xs, wv) \
        A.x = fmaf(xs, wv.x, A.x); A.y = fmaf(xs, wv.y, A.y); \
        A.z = fmaf(xs, wv.z, A.z); A.w = fmaf(xs, wv.w, A.w);
        FMA4(acc0, x0.x, w0) FMA4(acc0, x0.y, w1) FMA4(acc0, x0.z, w2) FMA4(acc0, x0.w, w3)
        FMA4(acc1, x1.x, w0) FMA4(acc1, x1.y, w1) FMA4(acc1, x1.z, w2) FMA4(acc1, x1.w, w3)
        FMA4(acc2, x2.x, w0) FMA4(acc2, x2.y, w1) FMA4(acc2, x2.z, w2) FMA4(acc2, x2.w, w3)
        FMA4(acc3, x3.x, w0) FMA4(acc3, x3.y, w1) FMA4(acc3, x3.z, w2) FMA4(acc3, x3.w, w3)
#undef FMA4
    }

#define EPI(A, i) { \
        int rg = rowbase + r0 + i; \
        if (rg < nrows) { \
            if (RELU) { \
                A.x = A.x > 0.f ? A.x : 0.01f * A.x; \
                A.y = A.y > 0.f ? A.y : 0.01f * A.y; \
                A.z = A.z > 0.f ? A.z : 0.01f * A.z; \
                A.w = A.w > 0.f ? A.w : 0.01f * A.w; \
            } \
            *reinterpret_cast<float4*>(out + (size_t)rg * 64 + c0) = A; \
        } }
    EPI(acc0, 0) EPI(acc1, 1) EPI(acc2, 2) EPI(acc3, 3)
#undef EPI
}

extern "C" void kernel_launch(void* const* d_in, const int* in_sizes, int n_in,
                              void* d_out, int out_size, void* d_ws, size_t ws_size,
                              hipStream_t stream) {
    const float* feat   = (const float*)d_in[0];
    const int*   esrc   = (const int*)d_in[1];
    const int*   edst   = (const int*)d_in[2];
    const int*   labels = (const int*)d_in[3];
    const float* W_lin  = (const float*)d_in[4];
    const float* b_lin  = (const float*)d_in[5];
    const float* W_lin1 = (const float*)d_in[6];
    const float* b_lin1 = (const float*)d_in[7];
    const float* W_th   = (const float*)d_in[8];
    const float* b_th   = (const float*)d_in[9];

    char* ws = (char*)d_ws;
    float* g0   = (float*)(ws + OFF_G0);
    float* g1   = (float*)(ws + OFF_G1);
    float* hs   = (float*)(ws + OFF_HS);
    unsigned int* csr = (unsigned int*)(ws + OFF_CSR);
    int* rp     = (int*)(ws + OFF_RP);
    unsigned int* cnt = (unsigned int*)(ws + OFF_CNT);
    float* d2o  = (float*)(ws + OFF_D2O);
    float* d2p  = (float*)(ws + OFF_D2P);
    float* d2n  = (float*)(ws + OFF_D2N);
    float* rdo  = (float*)(ws + OFF_RDO);
    float* rdp  = (float*)(ws + OFF_RDP);
    float* rdn  = (float*)(ws + OFF_RDN);
    float* dvo  = (float*)(ws + OFF_DVO);
    float* dvp  = (float*)(ws + OFF_DVP);
    float* dvn  = (float*)(ws + OFF_DVN);
    int* part   = (int*)(ws + OFF_PART);

    float* out0 = (float*)d_out;
    float* out1 = out0 + (size_t)N_NODES * 64;
    float* out2 = out1 + (size_t)N_NODES * 64;

    const float TH[4][3] = {{0.5f, -0.4f, 0.1f},
                            {0.25f, 0.5f, -0.25f},
                            {0.1f, 0.3f, 0.6f},
                            {0.05f, -0.2f, 0.8f}};

    const int EB = N_EDGES / 256;             // 6250
    const int NB = (N_NODES + 255) / 256;     // 391
    const int SB = (N_NODES + 255) / 256 + 1; // 392 (pad block for scan)
    const int HB = N_NODES / 4;               // 25000 blocks, 1 node/wave64
    const int GB = (N_NODES + 63) / 64;       // 1563 gemm blocks

    // packed degree counters
    hipMemsetAsync(cnt, 0, N_NODES * sizeof(int), stream);
    k_mask_deg<<<EB, 256, 0, stream>>>(esrc, edst, labels, cnt);
    k_dinv<<<NB, 256, 0, stream>>>(cnt, d2o, d2p, d2n, rdo, rdp, rdn, dvo, dvp, dvn);

    // CSR build: exclusive scan -> rp (start ptrs), tagged fill mutates rp -> end ptrs
    k_scan_a<<<SB, 256, 0, stream>>>(cnt, N_NODES, rp, part);
    k_scan_b<<<1, 512, 0, stream>>>(part, SB);
    k_scan_c<<<SB, 256, 0, stream>>>(rp, part, N_NODES);
    k_fill<<<EB, 256, 0, stream>>>(esrc, edst, labels, rp, csr);

    // ---- o-phase: 8 hops over all edges ----
    k_init_o<<<N_NODES * 32 / 256, 256, 0, stream>>>(feat, dvo, g0, hs);
    float* ga = g0; float* gb = g1;
    for (int hop = 0; hop < 8; ++hop) {
        int poly = hop >> 1, k = (hop & 1) + 1;
        int colA = poly * 32;
        float cA = TH[poly][k];
        int colB = -1; float cB = 0.f;
        if (k == 2 && poly < 3) { colB = (poly + 1) * 32; cB = TH[poly + 1][0]; }
        k_hop_o<<<HB, 256, 0, stream>>>(rp, csr, ga, gb, d2o, rdo, hs, colA, cA, colB, cB);
        float* t = ga; ga = gb; gb = t;
    }
    k_gemm<128, true><<<GB, 256, 0, stream>>>(hs, W_lin, b_lin, out0, N_NODES);

    // ---- pn-phase: 4 fused hops over tagged CSR ----
    k_init_pn<<<N_NODES * 32 / 256, 256, 0, stream>>>(feat, dvp, dvn, g0, hs);
    ga = g0; gb = g1;
    for (int hop = 0; hop < 4; ++hop) {
        int poly = hop >> 1, k = (hop & 1) + 1;
        int colAp = poly * 32;       float cAp = TH[poly][k];
        int colAn = 64 + poly * 32;  float cAn = TH[poly + 2][k];
        int colB = -1; float cBp = 0.f, cBn = 0.f;
        if (k == 2 && poly == 0) { colB = 32; cBp = TH[1][0]; cBn = TH[3][0]; }
        k_hop_pn<<<HB, 256, 0, stream>>>(rp, csr, ga, gb,
                                         d2p, d2n, rdp, rdn, hs,
                                         colAp, cAp, colAn, cAn, colB, cBp, cBn);
        float* t = ga; ga = gb; gb = t;
    }
    k_gemm<128, true><<<GB, 256, 0, stream>>>(hs, W_lin1, b_lin1, out1, N_NODES);

    // transh
    k_gemm<32, false><<<GB, 256, 0, stream>>>(feat, W_th, b_th, out2, N_NODES);
}

// Round 7
// 818.333 us; speedup vs baseline: 20.2439x; 1.0244x over previous
//
#include <hip/hip_runtime.h>

#define N_NODES 100000
#define N_EDGES 1600000

// ---- workspace layout (bytes) ----
#define OFF_G0    0UL            // g ping  [N,64] bf16 (o-phase uses [N,32])
#define OFF_G1    25600000UL     // g pong  [N,64] bf16
#define OFF_HS    51200000UL     // hs      [N,128] f32 (o-phase then pn-phase)
#define OFF_CSR   102400000UL    // tagged CSR: src | (neg<<31), [E] u32
#define OFF_RP    108800000UL    // rowptr/cursor [N] (+scan pad)
#define OFF_CNT   109300000UL    // packed deg<<16 | posdeg, [N] u32
#define OFF_D2O   110100000UL    // 1/clip(deg)     f32 [N]
#define OFF_D2P   110500000UL
#define OFF_D2N   110900000UL
#define OFF_RDO   111300000UL    // sqrt(clip(deg)) f32 [N]
#define OFF_RDP   111700000UL
#define OFF_RDN   112100000UL
#define OFF_DVO   112500000UL    // rsqrt(clip(deg)) f32 [N]
#define OFF_DVP   112900000UL
#define OFF_DVN   113300000UL
#define OFF_PART  113700000UL    // scan partials [392] int

__device__ __forceinline__ float bf2f(unsigned short h) {
    union { unsigned u; float f; } c; c.u = ((unsigned)h) << 16; return c.f;
}
__device__ __forceinline__ unsigned short f2bf(float x) {
    union { float f; unsigned u; } c; c.f = x;
    unsigned r = (c.u + 0x7FFFu + ((c.u >> 16) & 1u)) >> 16;
    return (unsigned short)r;
}

__global__ __launch_bounds__(256) void k_mask_deg(
    const int* __restrict__ src, const int* __restrict__ dst,
    const int* __restrict__ labels, unsigned int* __restrict__ cnt) {
    int e = blockIdx.x * 256 + threadIdx.x;
    int s = src[e], d = dst[e];
    unsigned int p = (labels[s] == labels[d]) ? 1u : 0u;
    atomicAdd(&cnt[d], 0x10000u + p);   // deg in hi16, posdeg in lo16
}

__global__ __launch_bounds__(256) void k_dinv(
    const unsigned int* __restrict__ cnt,
    float* __restrict__ d2o, float* __restrict__ d2p, float* __restrict__ d2n,
    float* __restrict__ rdo, float* __restrict__ rdp, float* __restrict__ rdn,
    float* __restrict__ dvo, float* __restrict__ dvp, float* __restrict__ dvn) {
    int v = blockIdx.x * 256 + threadIdx.x;
    if (v >= N_NODES) return;
    unsigned int c = cnt[v];
    int dg = (int)(c >> 16), pg = (int)(c & 0xFFFF), ng = dg - pg;
    float co = (float)max(dg, 1);
    float cp = (float)max(pg, 1);
    float cn = (float)max(ng, 1);
    d2o[v] = 1.f / co; rdo[v] = sqrtf(co); dvo[v] = rsqrtf(co);
    d2p[v] = 1.f / cp; rdp[v] = sqrtf(cp); dvp[v] = rsqrtf(cp);
    d2n[v] = 1.f / cn; rdn[v] = sqrtf(cn); dvn[v] = rsqrtf(cn);
}

// ---- exclusive prefix scan over deg (hi16 of cnt) ----
__global__ __launch_bounds__(256) void k_scan_a(
    const unsigned int* __restrict__ cnt, int n, int* __restrict__ out,
    int* __restrict__ partial) {
    __shared__ int tmp[256];
    int g = blockIdx.x * 256 + threadIdx.x;
    int v = (g < n) ? (int)(cnt[g] >> 16) : 0;
    tmp[threadIdx.x] = v;
    __syncthreads();
    for (int off = 1; off < 256; off <<= 1) {
        int t = (threadIdx.x >= off) ? tmp[threadIdx.x - off] : 0;
        __syncthreads();
        tmp[threadIdx.x] += t;
        __syncthreads();
    }
    out[g] = tmp[threadIdx.x] - v;   // exclusive
    if (threadIdx.x == 255) partial[blockIdx.x] = tmp[255];
}

__global__ __launch_bounds__(512) void k_scan_b(int* __restrict__ partial, int nb) {
    __shared__ int tmp[512];
    int v = (threadIdx.x < nb) ? partial[threadIdx.x] : 0;
    tmp[threadIdx.x] = v;
    __syncthreads();
    for (int off = 1; off < 512; off <<= 1) {
        int t = (threadIdx.x >= off) ? tmp[threadIdx.x - off] : 0;
        __syncthreads();
        tmp[threadIdx.x] += t;
        __syncthreads();
    }
    if (threadIdx.x < nb) partial[threadIdx.x] = tmp[threadIdx.x] - v;
}

__global__ __launch_bounds__(256) void k_scan_c(
    int* __restrict__ out, const int* __restrict__ partial, int n) {
    int g = blockIdx.x * 256 + threadIdx.x;
    if (g < n) out[g] += partial[blockIdx.x];
}

// fill uses rp as cursors; after fill, rp[v] == end-of-row v (start of v+1)
__global__ __launch_bounds__(256) void k_fill(
    const int* __restrict__ src, const int* __restrict__ dst,
    const int* __restrict__ labels, int* __restrict__ rp,
    unsigned int* __restrict__ csr) {
    int e = blockIdx.x * 256 + threadIdx.x;
    int s = src[e], d = dst[e];
    unsigned int tag = (labels[s] == labels[d]) ? 0u : 0x80000000u;
    csr[atomicAdd(&rp[d], 1)] = (unsigned int)s | tag;
}

// ---- phase inits: g = bf16(feat * dinv) ----
__global__ __launch_bounds__(256) void k_init_o(
    const float* __restrict__ feat, const float* __restrict__ dvo,
    unsigned short* __restrict__ g0, float* __restrict__ hs) {
    int idx = blockIdx.x * 256 + threadIdx.x;   // over N*32
    int v = idx >> 5, c = idx & 31;
    float x = feat[idx];
    g0[idx] = f2bf(x * dvo[v]);
    hs[v * 128 + c] = 0.5f * x;                 // THETAS[0][0]
}

__global__ __launch_bounds__(256) void k_init_pn(
    const float* __restrict__ feat, const float* __restrict__ dvp, const float* __restrict__ dvn,
    unsigned short* __restrict__ g0, float* __restrict__ hs) {
    int idx = blockIdx.x * 256 + threadIdx.x;   // over N*32
    int v = idx >> 5, c = idx & 31;
    float x = feat[idx];
    g0[v * 64 + c]      = f2bf(x * dvp[v]);
    g0[v * 64 + 32 + c] = f2bf(x * dvn[v]);
    hs[v * 128 + c]      = 0.5f * x;            // THETAS[0][0] (p head)
    hs[v * 128 + 64 + c] = 0.1f * x;            // THETAS[2][0] (n head)
}

// ---- o-hop: 1 node per wave64; 8 edge-slots x 8 lanes, bf16x4 gathers ----
__global__ __launch_bounds__(256) void k_hop_o(
    const int* __restrict__ rowend, const unsigned int* __restrict__ csr,
    const unsigned short* __restrict__ g_old, unsigned short* __restrict__ g_new,
    const float* __restrict__ d2, const float* __restrict__ rd,
    float* __restrict__ hs, int colA, float cA, int colB, float cB) {
    int v = (blockIdx.x * 256 + threadIdx.x) >> 6;
    int lane = threadIdx.x & 63;
    int slot = lane >> 3, fl = lane & 7;
    int beg = v ? rowend[v - 1] : 0;
    int end = rowend[v];
    float4 acc = make_float4(0.f, 0.f, 0.f, 0.f);
    const ushort4* gp = reinterpret_cast<const ushort4*>(g_old);
    for (int i = beg + slot; i < end; i += 8) {
        int s = (int)(csr[i] & 0x7FFFFFFFu);
        ushort4 h = gp[s * 8 + fl];
        acc.x += bf2f(h.x); acc.y += bf2f(h.y);
        acc.z += bf2f(h.z); acc.w += bf2f(h.w);
    }
    for (int m = 8; m < 64; m <<= 1) {
        acc.x += __shfl_xor(acc.x, m);
        acc.y += __shfl_xor(acc.y, m);
        acc.z += __shfl_xor(acc.z, m);
        acc.w += __shfl_xor(acc.w, m);
    }
    if (slot == 0) {
        float dd = d2[v], rr = rd[v];
        ushort4 gh = gp[v * 8 + fl];
        float4 gn;
        gn.x = bf2f(gh.x) - acc.x * dd; gn.y = bf2f(gh.y) - acc.y * dd;
        gn.z = bf2f(gh.z) - acc.z * dd; gn.w = bf2f(gh.w) - acc.w * dd;
        ushort4 go;
        go.x = f2bf(gn.x); go.y = f2bf(gn.y); go.z = f2bf(gn.z); go.w = f2bf(gn.w);
        reinterpret_cast<ushort4*>(g_new)[v * 8 + fl] = go;
        float4 fn;
        fn.x = gn.x * rr; fn.y = gn.y * rr; fn.z = gn.z * rr; fn.w = gn.w * rr;
        float4* hp = reinterpret_cast<float4*>(hs + v * 128 + colA) + fl;
        float4 h = *hp;
        h.x += cA * fn.x; h.y += cA * fn.y; h.z += cA * fn.z; h.w += cA * fn.w;
        *hp = h;
        if (colB >= 0) {
            float4 hb;
            hb.x = cB * fn.x; hb.y = cB * fn.y; hb.z = cB * fn.z; hb.w = cB * fn.w;
            reinterpret_cast<float4*>(hs + v * 128 + colB)[fl] = hb;
        }
    }
}

// ---- pn-hop: 1 node per wave64, tagged CSR, dual accumulators, bf16 ----
__global__ __launch_bounds__(256) void k_hop_pn(
    const int* __restrict__ rowend, const unsigned int* __restrict__ csr,
    const unsigned short* __restrict__ g_old, unsigned short* __restrict__ g_new,
    const float* __restrict__ d2p, const float* __restrict__ d2n,
    const float* __restrict__ rdp, const float* __restrict__ rdn,
    float* __restrict__ hs,
    int colAp, float cAp, int colAn, float cAn,
    int colB, float cBp, float cBn) {
    int v = (blockIdx.x * 256 + threadIdx.x) >> 6;
    int lane = threadIdx.x & 63;
    int slot = lane >> 3, fl = lane & 7;
    int beg = v ? rowend[v - 1] : 0;
    int end = rowend[v];
    float4 ap = make_float4(0.f, 0.f, 0.f, 0.f);
    float4 an = make_float4(0.f, 0.f, 0.f, 0.f);
    const ushort4* gp = reinterpret_cast<const ushort4*>(g_old);
    for (int i = beg + slot; i < end; i += 8) {
        unsigned int e = csr[i];
        int s = (int)(e & 0x7FFFFFFFu);
        int neg = (int)(e >> 31);
        ushort4 h = gp[s * 16 + (neg << 3) + fl];
        float4 val;
        val.x = bf2f(h.x); val.y = bf2f(h.y); val.z = bf2f(h.z); val.w = bf2f(h.w);
        float w = neg ? 0.f : 1.f;
        float u = 1.f - w;
        ap.x += w * val.x; ap.y += w * val.y; ap.z += w * val.z; ap.w += w * val.w;
        an.x += u * val.x; an.y += u * val.y; an.z += u * val.z; an.w += u * val.w;
    }
    for (int m = 8; m < 64; m <<= 1) {
        ap.x += __shfl_xor(ap.x, m); ap.y += __shfl_xor(ap.y, m);
        ap.z += __shfl_xor(ap.z, m); ap.w += __shfl_xor(ap.w, m);
        an.x += __shfl_xor(an.x, m); an.y += __shfl_xor(an.y, m);
        an.z += __shfl_xor(an.z, m); an.w += __shfl_xor(an.w, m);
    }
    if (slot == 0) {
        float dd = d2p[v], rr = rdp[v];
        ushort4 gh = gp[v * 16 + fl];
        float4 gn;
        gn.x = bf2f(gh.x) - ap.x * dd; gn.y = bf2f(gh.y) - ap.y * dd;
        gn.z = bf2f(gh.z) - ap.z * dd; gn.w = bf2f(gh.w) - ap.w * dd;
        ushort4 go;
        go.x = f2bf(gn.x); go.y = f2bf(gn.y); go.z = f2bf(gn.z); go.w = f2bf(gn.w);
        reinterpret_cast<ushort4*>(g_new)[v * 16 + fl] = go;
        float4 fn;
        fn.x = gn.x * rr; fn.y = gn.y * rr; fn.z = gn.z * rr; fn.w = gn.w * rr;
        float4* hp = reinterpret_cast<float4*>(hs + v * 128 + colAp) + fl;
        float4 h = *hp;
        h.x += cAp * fn.x; h.y += cAp * fn.y; h.z += cAp * fn.z; h.w += cAp * fn.w;
        *hp = h;
        if (colB >= 0) {
            float4 hb;
            hb.x = cBp * fn.x; hb.y = cBp * fn.y; hb.z = cBp * fn.z; hb.w = cBp * fn.w;
            reinterpret_cast<float4*>(hs + v * 128 + colB)[fl] = hb;
        }
    } else if (slot == 1) {
        float dd = d2n[v], rr = rdn[v];
        ushort4 gh = gp[v * 16 + 8 + fl];
        float4 gn;
        gn.x = bf2f(gh.x) - an.x * dd; gn.y = bf2f(gh.y) - an.y * dd;
        gn.z = bf2f(gh.z) - an.z * dd; gn.w = bf2f(gh.w) - an.w * dd;
        ushort4 go;
        go.x = f2bf(gn.x); go.y = f2bf(gn.y); go.z = f2bf(gn.z); go.w = f2bf(gn.w);
        reinterpret_cast<ushort4*>(g_new)[v * 16 + 8 + fl] = go;
        float4 fn;
        fn.x = gn.x * rr; fn.y = gn.y * rr; fn.z = gn.z * rr; fn.w = gn.w * rr;
        float4* hp = reinterpret_cast<float4*>(hs + v * 128 + colAn) + fl;
        float4 h = *hp;
        h.x += cAn * fn.x; h.y += cAn * fn.y; h.z += cAn * fn.z; h.w += cAn * fn.w;
        *hp = h;
        if (colB >= 0) {
            float4 hb;
            hb.x = cBn * fn.x; hb.y = cBn * fn.y; hb.z = cBn * fn.z; hb.w = cBn * fn.w;
            reinterpret_cast<float4*>(hs + v * 128 + colB + 64)[fl] = hb;
        }
    }
}

// ---- GEMM: out[N,64] = act(X[N,KDIM] @ W[KDIM,64] + b) ----
// 64 rows/block, 256 threads, 4x4 register tile per thread.
template <int KDIM, bool RELU>
__global__ __launch_bounds__(256) void k_gemm(
    const float* __restrict__ X, const float* __restrict__ W,
    const float* __restrict__ bias, float* __restrict__ out, int nrows) {
    constexpr int SXP = KDIM + 4;
    __shared__ float sW[KDIM * 64];
    __shared__ float sX[64 * SXP];
    int tid = threadIdx.x;
    int rowbase = blockIdx.x * 64;

    for (int i = tid; i < KDIM * 16; i += 256)
        reinterpret_cast<float4*>(sW)[i] = reinterpret_cast<const float4*>(W)[i];

    constexpr int QF4 = KDIM / 4;
    constexpr int RPP = 256 / QF4;
    int q = tid & (QF4 - 1);
    int rloc = tid / QF4;
#pragma unroll
    for (int pass = 0; pass < 64 / RPP; ++pass) {
        int r = rloc + pass * RPP;
        int rg = rowbase + r;
        float4 v = make_float4(0.f, 0.f, 0.f, 0.f);
        if (rg < nrows) v = reinterpret_cast<const float4*>(X + (size_t)rg * KDIM)[q];
        float* dst = sX + r * SXP + q * 4;
        dst[0] = v.x; dst[1] = v.y; dst[2] = v.z; dst[3] = v.w;
    }
    __syncthreads();

    int c0 = (tid & 15) * 4;
    int r0 = (tid >> 4) * 4;
    float4 bv = reinterpret_cast<const float4*>(bias)[tid & 15];
    float4 acc0 = bv, acc1 = bv, acc2 = bv, acc3 = bv;

#pragma unroll 4
    for (int k4 = 0; k4 < KDIM / 4; ++k4) {
        int k = k4 * 4;
        float4 x0 = *reinterpret_cast<const float4*>(sX + (r0 + 0) * SXP + k);
        float4 x1 = *reinterpret_cast<const float4*>(sX + (r0 + 1) * SXP + k);
        float4 x2 = *reinterpret_cast<const float4*>(sX + (r0 + 2) * SXP + k);
        float4 x3 = *reinterpret_cast<const float4*>(sX + (r0 + 3) * SXP + k);
        float4 w0 = *reinterpret_cast<const float4*>(sW + (k + 0) * 64 + c0);
        float4 w1 = *reinterpret_cast<const float4*>(sW + (k + 1) * 64 + c0);
        float4 w2 = *reinterpret_cast<const float4*>(sW + (k + 2) * 64 + c0);
        float4 w3 = *reinterpret_cast<const float4*>(sW + (k + 3) * 64 + c0);
#define FMA4(A, xs, wv) \
        A.x = fmaf(xs, wv.x, A.x); A.y = fmaf(xs, wv.y, A.y); \
        A.z = fmaf(xs, wv.z, A.z); A.w = fmaf(xs, wv.w, A.w);
        FMA4(acc0, x0.x, w0) FMA4(acc0, x0.y, w1) FMA4(acc0, x0.z, w2) FMA4(acc0, x0.w, w3)
        FMA4(acc1, x1.x, w0) FMA4(acc1, x1.y, w1) FMA4(acc1, x1.z, w2) FMA4(acc1, x1.w, w3)
        FMA4(acc2, x2.x, w0) FMA4(acc2, x2.y, w1) FMA4(acc2, x2.z, w2) FMA4(acc2, x2.w, w3)
        FMA4(acc3, x3.x, w0) FMA4(acc3, x3.y, w1) FMA4(acc3, x3.z, w2) FMA4(acc3, x3.w, w3)
#undef FMA4
    }

#define EPI(A, i) { \
        int rg = rowbase + r0 + i; \
        if (rg < nrows) { \
            if (RELU) { \
                A.x = A.x > 0.f ? A.x : 0.01f * A.x; \
                A.y = A.y > 0.f ? A.y : 0.01f * A.y; \
                A.z = A.z > 0.f ? A.z : 0.01f * A.z; \
                A.w = A.w > 0.f ? A.w : 0.01f * A.w; \
            } \
            *reinterpret_cast<float4*>(out + (size_t)rg * 64 + c0) = A; \
        } }
    EPI(acc0, 0) EPI(acc1, 1) EPI(acc2, 2) EPI(acc3, 3)
#undef EPI
}

extern "C" void kernel_launch(void* const* d_in, const int* in_sizes, int n_in,
                              void* d_out, int out_size, void* d_ws, size_t ws_size,
                              hipStream_t stream) {
    const float* feat   = (const float*)d_in[0];
    const int*   esrc   = (const int*)d_in[1];
    const int*   edst   = (const int*)d_in[2];
    const int*   labels = (const int*)d_in[3];
    const float* W_lin  = (const float*)d_in[4];
    const float* b_lin  = (const float*)d_in[5];
    const float* W_lin1 = (const float*)d_in[6];
    const float* b_lin1 = (const float*)d_in[7];
    const float* W_th   = (const float*)d_in[8];
    const float* b_th   = (const float*)d_in[9];

    char* ws = (char*)d_ws;
    unsigned short* g0 = (unsigned short*)(ws + OFF_G0);
    unsigned short* g1 = (unsigned short*)(ws + OFF_G1);
    float* hs   = (float*)(ws + OFF_HS);
    unsigned int* csr = (unsigned int*)(ws + OFF_CSR);
    int* rp     = (int*)(ws + OFF_RP);
    unsigned int* cnt = (unsigned int*)(ws + OFF_CNT);
    float* d2o  = (float*)(ws + OFF_D2O);
    float* d2p  = (float*)(ws + OFF_D2P);
    float* d2n  = (float*)(ws + OFF_D2N);
    float* rdo  = (float*)(ws + OFF_RDO);
    float* rdp  = (float*)(ws + OFF_RDP);
    float* rdn  = (float*)(ws + OFF_RDN);
    float* dvo  = (float*)(ws + OFF_DVO);
    float* dvp  = (float*)(ws + OFF_DVP);
    float* dvn  = (float*)(ws + OFF_DVN);
    int* part   = (int*)(ws + OFF_PART);

    float* out0 = (float*)d_out;
    float* out1 = out0 + (size_t)N_NODES * 64;
    float* out2 = out1 + (size_t)N_NODES * 64;

    const float TH[4][3] = {{0.5f, -0.4f, 0.1f},
                            {0.25f, 0.5f, -0.25f},
                            {0.1f, 0.3f, 0.6f},
                            {0.05f, -0.2f, 0.8f}};

    const int EB = N_EDGES / 256;             // 6250
    const int NB = (N_NODES + 255) / 256;     // 391
    const int SB = (N_NODES + 255) / 256 + 1; // 392 (pad block for scan)
    const int HB = N_NODES / 4;               // 25000 blocks, 1 node/wave64
    const int GB = (N_NODES + 63) / 64;       // 1563 gemm blocks

    // packed degree counters
    hipMemsetAsync(cnt, 0, N_NODES * sizeof(int), stream);
    k_mask_deg<<<EB, 256, 0, stream>>>(esrc, edst, labels, cnt);
    k_dinv<<<NB, 256, 0, stream>>>(cnt, d2o, d2p, d2n, rdo, rdp, rdn, dvo, dvp, dvn);

    // CSR build: exclusive scan -> rp (start ptrs), tagged fill mutates rp -> end ptrs
    k_scan_a<<<SB, 256, 0, stream>>>(cnt, N_NODES, rp, part);
    k_scan_b<<<1, 512, 0, stream>>>(part, SB);
    k_scan_c<<<SB, 256, 0, stream>>>(rp, part, N_NODES);
    k_fill<<<EB, 256, 0, stream>>>(esrc, edst, labels, rp, csr);

    // ---- o-phase: 8 hops over all edges ----
    k_init_o<<<N_NODES * 32 / 256, 256, 0, stream>>>(feat, dvo, g0, hs);
    unsigned short* ga = g0; unsigned short* gb = g1;
    for (int hop = 0; hop < 8; ++hop) {
        int poly = hop >> 1, k = (hop & 1) + 1;
        int colA = poly * 32;
        float cA = TH[poly][k];
        int colB = -1; float cB = 0.f;
        if (k == 2 && poly < 3) { colB = (poly + 1) * 32; cB = TH[poly + 1][0]; }
        k_hop_o<<<HB, 256, 0, stream>>>(rp, csr, ga, gb, d2o, rdo, hs, colA, cA, colB, cB);
        unsigned short* t = ga; ga = gb; gb = t;
    }
    k_gemm<128, true><<<GB, 256, 0, stream>>>(hs, W_lin, b_lin, out0, N_NODES);

    // ---- pn-phase: 4 fused hops over tagged CSR ----
    k_init_pn<<<N_NODES * 32 / 256, 256, 0, stream>>>(feat, dvp, dvn, g0, hs);
    ga = g0; gb = g1;
    for (int hop = 0; hop < 4; ++hop) {
        int poly = hop >> 1, k = (hop & 1) + 1;
        int colAp = poly * 32;       float cAp = TH[poly][k];
        int colAn = 64 + poly * 32;  float cAn = TH[poly + 2][k];
        int colB = -1; float cBp = 0.f, cBn = 0.f;
        if (k == 2 && poly == 0) { colB = 32; cBp = TH[1][0]; cBn = TH[3][0]; }
        k_hop_pn<<<HB, 256, 0, stream>>>(rp, csr, ga, gb,
                                         d2p, d2n, rdp, rdn, hs,
                                         colAp, cAp, colAn, cAn, colB, cBp, cBn);
        unsigned short* t = ga; ga = gb; gb = t;
    }
    k_gemm<128, true><<<GB, 256, 0, stream>>>(hs, W_lin1, b_lin1, out1, N_NODES);

    // transh
    k_gemm<32, false><<<GB, 256, 0, stream>>>(feat, W_th, b_th, out2, N_NODES);
}